// Round 2
// baseline (3163.945 us; speedup 1.0000x reference)
//
#include <hip/hip_runtime.h>
#include <hip/hip_bf16.h>
#include <math.h>

#define N_NODES 50000
#define N_EDGES 800000
#define FEAT 90
#define HD 128
#define STEPS 4
#define N_GRAPHS 100

__device__ __forceinline__ float sigmoid_(float x) { return 1.f / (1.f + expf(-x)); }

// ---------------- CSR build ----------------
__global__ void k_count(const int* __restrict__ dst, int* __restrict__ deg) {
    int e = blockIdx.x * 256 + threadIdx.x;
    if (e < N_EDGES) atomicAdd(&deg[dst[e]], 1);
}

__global__ void k_scan(const int* __restrict__ deg, int* __restrict__ row_start,
                       int* __restrict__ cursor) {
    __shared__ int sd[1024];
    __shared__ int carry_s;
    int t = threadIdx.x;
    if (t == 0) carry_s = 0;
    __syncthreads();
    for (int base = 0; base < N_NODES; base += 1024) {
        int v = base + t;
        int x = (v < N_NODES) ? deg[v] : 0;
        sd[t] = x;
        __syncthreads();
        for (int off = 1; off < 1024; off <<= 1) {
            int y = (t >= off) ? sd[t - off] : 0;
            __syncthreads();
            sd[t] += y;
            __syncthreads();
        }
        int carry = carry_s;
        int excl = carry + sd[t] - x;
        if (v < N_NODES) { row_start[v] = excl; cursor[v] = excl; }
        __syncthreads();
        if (t == 1023) carry_s = carry + sd[1023];
        __syncthreads();
    }
    if (t == 0) row_start[N_NODES] = carry_s;
}

__global__ void k_fill(const int* __restrict__ src, const int* __restrict__ dst,
                       int* __restrict__ cursor, int* __restrict__ esrc) {
    int e = blockIdx.x * 256 + threadIdx.x;
    if (e < N_EDGES) {
        int p = atomicAdd(&cursor[dst[e]], 1);
        esrc[p] = src[e];
    }
}

// ---------------- Embedding: h = relu(x @ Wemb), x[N,90], Wemb[90,128] ----------------
__global__ __launch_bounds__(256) void k_embed(const float* __restrict__ x,
                                               const float* __restrict__ Wemb,
                                               float* __restrict__ h) {
    __shared__ __align__(16) float a_s[32 * 96];
    __shared__ __align__(16) float w_s[96 * 128];
    int t = threadIdx.x;
    int n0 = blockIdx.x * 32;
    for (int i = t; i < 96 * 128; i += 256) {
        int k = i >> 7;
        w_s[i] = (k < FEAT) ? Wemb[i] : 0.f;
    }
    for (int i = t; i < 32 * 96; i += 256) {
        int r = i / 96, k = i - r * 96;
        int n = n0 + r;
        a_s[i] = (k < FEAT && n < N_NODES) ? x[(size_t)n * FEAT + k] : 0.f;
    }
    __syncthreads();
    int tx = t & 63, rg = t >> 6;
    float acc[8][2];
#pragma unroll
    for (int r = 0; r < 8; ++r) { acc[r][0] = 0.f; acc[r][1] = 0.f; }
    for (int k0 = 0; k0 < 96; k0 += 4) {
        float a4[8][4];
#pragma unroll
        for (int r = 0; r < 8; ++r)
            *(float4*)a4[r] = *(const float4*)&a_s[(rg * 8 + r) * 96 + k0];
#pragma unroll
        for (int j = 0; j < 4; ++j) {
            float w0 = w_s[(k0 + j) * 128 + tx];
            float w1 = w_s[(k0 + j) * 128 + tx + 64];
#pragma unroll
            for (int r = 0; r < 8; ++r) {
                acc[r][0] += a4[r][j] * w0;
                acc[r][1] += a4[r][j] * w1;
            }
        }
    }
#pragma unroll
    for (int r = 0; r < 8; ++r) {
        int n = n0 + rg * 8 + r;
        if (n < N_NODES) {
            h[(size_t)n * HD + tx]      = fmaxf(acc[r][0], 0.f);
            h[(size_t)n * HD + tx + 64] = fmaxf(acc[r][1], 0.f);
        }
    }
}

// ---------------- msg GEMM: C = A[N,128] @ B[128,128] ----------------
__global__ __launch_bounds__(256) void k_gemm128(const float* __restrict__ A,
                                                 const float* __restrict__ B,
                                                 float* __restrict__ C) {
    __shared__ __align__(16) float a_s[32 * 128];
    __shared__ __align__(16) float w_s[128 * 128];
    int t = threadIdx.x;
    int n0 = blockIdx.x * 32;
    for (int i = t * 4; i < 128 * 128; i += 1024)
        *(float4*)&w_s[i] = *(const float4*)&B[i];
    for (int i = t * 4; i < 32 * 128; i += 1024) {
        int r = i >> 7;
        float4 v = make_float4(0.f, 0.f, 0.f, 0.f);
        if (n0 + r < N_NODES) v = *(const float4*)&A[(size_t)n0 * HD + i];
        *(float4*)&a_s[i] = v;
    }
    __syncthreads();
    int tx = t & 63, rg = t >> 6;
    float acc[8][2];
#pragma unroll
    for (int r = 0; r < 8; ++r) { acc[r][0] = 0.f; acc[r][1] = 0.f; }
    for (int k0 = 0; k0 < 128; k0 += 4) {
        float a4[8][4];
#pragma unroll
        for (int r = 0; r < 8; ++r)
            *(float4*)a4[r] = *(const float4*)&a_s[(rg * 8 + r) * 128 + k0];
#pragma unroll
        for (int j = 0; j < 4; ++j) {
            float w0 = w_s[(k0 + j) * 128 + tx];
            float w1 = w_s[(k0 + j) * 128 + tx + 64];
#pragma unroll
            for (int r = 0; r < 8; ++r) {
                acc[r][0] += a4[r][j] * w0;
                acc[r][1] += a4[r][j] * w1;
            }
        }
    }
#pragma unroll
    for (int r = 0; r < 8; ++r) {
        int n = n0 + rg * 8 + r;
        if (n < N_NODES) {
            C[(size_t)n * HD + tx]      = acc[r][0];
            C[(size_t)n * HD + tx + 64] = acc[r][1];
        }
    }
}

// ---------------- CSR gather-sum: agg[v] = sum over incoming edges of m[src] ----------------
__global__ __launch_bounds__(256) void k_agg(const float* __restrict__ m,
                                             const int* __restrict__ row_start,
                                             const int* __restrict__ esrc,
                                             float* __restrict__ agg) {
    int c = threadIdx.x & 127;
    int half = threadIdx.x >> 7;
    int v = blockIdx.x * 2 + half;
    int beg = row_start[v], end = row_start[v + 1];
    float acc0 = 0.f, acc1 = 0.f;
    int j = beg;
    for (; j + 2 <= end; j += 2) {
        int s0 = esrc[j], s1 = esrc[j + 1];
        float v0 = m[(size_t)s0 * HD + c];
        float v1 = m[(size_t)s1 * HD + c];
        acc0 += v0;
        acc1 += v1;
    }
    if (j < end) acc0 += m[(size_t)esrc[j] * HD + c];
    agg[(size_t)v * HD + c] = acc0 + acc1;
}

// ---------------- fused GRU: h = GRU(agg, h) ----------------
#define KC 16
__global__ __launch_bounds__(256) void k_gru(const float* __restrict__ agg,
                                             float* __restrict__ h,
                                             const float* __restrict__ Wih,
                                             const float* __restrict__ Whh,
                                             const float* __restrict__ bih,
                                             const float* __restrict__ bhh) {
    __shared__ __align__(16) float a_s[32 * 128];
    __shared__ __align__(16) float h_s[32 * 128];
    __shared__ __align__(16) float wi_s[KC * 384];
    __shared__ __align__(16) float wh_s[KC * 384];
    int t = threadIdx.x;
    int n0 = blockIdx.x * 32;
    for (int i = t * 4; i < 32 * 128; i += 1024) {
        int r = i >> 7;
        float4 va = make_float4(0.f, 0.f, 0.f, 0.f), vh = va;
        if (n0 + r < N_NODES) {
            va = *(const float4*)&agg[(size_t)n0 * HD + i];
            vh = *(const float4*)&h[(size_t)n0 * HD + i];
        }
        *(float4*)&a_s[i] = va;
        *(float4*)&h_s[i] = vh;
    }
    int tx = t & 63, rg = t >> 6;
    float ar[8][2] = {}, az[8][2] = {}, axn[8][2] = {}, ahn[8][2] = {};
    for (int k0 = 0; k0 < 128; k0 += KC) {
        if (k0) __syncthreads();
        for (int i = t * 4; i < KC * 384; i += 1024) {
            *(float4*)&wi_s[i] = *(const float4*)&Wih[(size_t)k0 * 384 + i];
            *(float4*)&wh_s[i] = *(const float4*)&Whh[(size_t)k0 * 384 + i];
        }
        __syncthreads();
#pragma unroll
        for (int kk = 0; kk < KC; kk += 4) {
            float a4[8][4], h4[8][4];
#pragma unroll
            for (int r = 0; r < 8; ++r) {
                *(float4*)a4[r] = *(const float4*)&a_s[(rg * 8 + r) * 128 + k0 + kk];
                *(float4*)h4[r] = *(const float4*)&h_s[(rg * 8 + r) * 128 + k0 + kk];
            }
#pragma unroll
            for (int j = 0; j < 4; ++j) {
                int kw = kk + j;
#pragma unroll
                for (int ci = 0; ci < 2; ++ci) {
                    int c = tx + 64 * ci;
                    float wir = wi_s[kw * 384 + c];
                    float wiz = wi_s[kw * 384 + c + 128];
                    float win = wi_s[kw * 384 + c + 256];
                    float whr = wh_s[kw * 384 + c];
                    float whz = wh_s[kw * 384 + c + 128];
                    float whn = wh_s[kw * 384 + c + 256];
#pragma unroll
                    for (int r = 0; r < 8; ++r) {
                        ar[r][ci]  += a4[r][j] * wir + h4[r][j] * whr;
                        az[r][ci]  += a4[r][j] * wiz + h4[r][j] * whz;
                        axn[r][ci] += a4[r][j] * win;
                        ahn[r][ci] += h4[r][j] * whn;
                    }
                }
            }
        }
    }
#pragma unroll
    for (int ci = 0; ci < 2; ++ci) {
        int c = tx + 64 * ci;
        float bir = bih[c], biz = bih[c + 128], bin_ = bih[c + 256];
        float bhr = bhh[c], bhz = bhh[c + 128], bhn = bhh[c + 256];
#pragma unroll
        for (int r = 0; r < 8; ++r) {
            int n = n0 + rg * 8 + r;
            if (n >= N_NODES) continue;
            float rg_ = sigmoid_(ar[r][ci] + bir + bhr);
            float z   = sigmoid_(az[r][ci] + biz + bhz);
            float nn  = tanhf(axn[r][ci] + bin_ + rg_ * (ahn[r][ci] + bhn));
            float hold = h_s[(rg * 8 + r) * 128 + c];
            h[(size_t)n * HD + c] = (1.f - z) * nn + z * hold;
        }
    }
}

// ---------------- pooling ----------------
__global__ void k_counts(const int* __restrict__ batch, int* __restrict__ counts) {
    int n = blockIdx.x * 256 + threadIdx.x;
    if (n < N_NODES) atomicAdd(&counts[batch[n]], 1);
}

#define POOL_CHUNK 256
__global__ __launch_bounds__(128) void k_pool(const float* __restrict__ h,
                                              const int* __restrict__ batch,
                                              float* __restrict__ pooled) {
    int t = threadIdx.x;  // 128 cols
    int n0 = blockIdx.x * POOL_CHUNK;
    int nend = n0 + POOL_CHUNK;
    if (nend > N_NODES) nend = N_NODES;
    float acc = 0.f;
    int cur = batch[n0];
    for (int n = n0; n < nend; ++n) {
        int g = batch[n];
        if (g != cur) {
            atomicAdd(&pooled[(size_t)cur * HD + t], acc);
            acc = 0.f;
            cur = g;
        }
        acc += fmaxf(h[(size_t)n * HD + t], 0.f);  // fused final relu
    }
    atomicAdd(&pooled[(size_t)cur * HD + t], acc);
}

// ---------------- output MLP ----------------
__global__ __launch_bounds__(128) void k_out(const float* __restrict__ pooled,
                                             const int* __restrict__ counts,
                                             const float* __restrict__ W1,
                                             const float* __restrict__ b1,
                                             const float* __restrict__ W2,
                                             const float* __restrict__ b2,
                                             float* __restrict__ out) {
    __shared__ float row[128];
    __shared__ float red[128];
    int t = threadIdx.x;
    int g = blockIdx.x;
    float cnt = (float)counts[g];
    if (cnt < 1.f) cnt = 1.f;
    row[t] = pooled[(size_t)g * HD + t] / cnt;
    __syncthreads();
    float acc = b1[t];
#pragma unroll 4
    for (int k = 0; k < HD; ++k) acc += row[k] * W1[k * HD + t];
    float hv = fmaxf(acc, 0.f);
    red[t] = hv * W2[t];
    __syncthreads();
    for (int off = 64; off > 0; off >>= 1) {
        if (t < off) red[t] += red[t + off];
        __syncthreads();
    }
    if (t == 0) {
        float xv = red[0] + b2[0];
        out[g] = fmaxf(xv, 0.f) + log1pf(expf(-fabsf(xv)));
    }
}

extern "C" void kernel_launch(void* const* d_in, const int* in_sizes, int n_in,
                              void* d_out, int out_size, void* d_ws, size_t ws_size,
                              hipStream_t stream) {
    (void)in_sizes; (void)n_in; (void)out_size; (void)ws_size;
    const float* x    = (const float*)d_in[0];
    const int*   ei   = (const int*)d_in[1];
    const int*   batch= (const int*)d_in[2];
    const float* Wemb = (const float*)d_in[3];
    const float* Wmsg = (const float*)d_in[4];
    const float* Wih  = (const float*)d_in[5];
    const float* Whh  = (const float*)d_in[6];
    const float* bih  = (const float*)d_in[7];
    const float* bhh  = (const float*)d_in[8];
    const float* W1   = (const float*)d_in[9];
    const float* b1   = (const float*)d_in[10];
    const float* W2   = (const float*)d_in[11];
    const float* b2   = (const float*)d_in[12];
    float* out = (float*)d_out;

    const int* e_src = ei;
    const int* e_dst = ei + N_EDGES;

    char* ws = (char*)d_ws;
    size_t off = 0;
    auto alloc = [&](size_t bytes) -> void* {
        void* p = ws + off;
        off = (off + bytes + 255) & ~(size_t)255;
        return p;
    };
    float* h      = (float*)alloc((size_t)N_NODES * HD * 4);
    float* m      = (float*)alloc((size_t)N_NODES * HD * 4);
    float* agg    = (float*)alloc((size_t)N_NODES * HD * 4);
    float* pooled = (float*)alloc((size_t)N_GRAPHS * HD * 4);
    int* deg      = (int*)alloc((size_t)N_NODES * 4);
    int* row_start= (int*)alloc((size_t)(N_NODES + 1) * 4);
    int* cursor   = (int*)alloc((size_t)N_NODES * 4);
    int* esrc     = (int*)alloc((size_t)N_EDGES * 4);
    int* counts   = (int*)alloc((size_t)N_GRAPHS * 4);

    hipMemsetAsync(deg, 0, (size_t)N_NODES * 4, stream);
    hipMemsetAsync(counts, 0, (size_t)N_GRAPHS * 4, stream);
    hipMemsetAsync(pooled, 0, (size_t)N_GRAPHS * HD * 4, stream);

    k_count<<<(N_EDGES + 255) / 256, 256, 0, stream>>>(e_dst, deg);
    k_scan<<<1, 1024, 0, stream>>>(deg, row_start, cursor);
    k_fill<<<(N_EDGES + 255) / 256, 256, 0, stream>>>(e_src, e_dst, cursor, esrc);

    k_embed<<<(N_NODES + 31) / 32, 256, 0, stream>>>(x, Wemb, h);

    for (int i = 0; i < STEPS; ++i) {
        k_gemm128<<<(N_NODES + 31) / 32, 256, 0, stream>>>(h, Wmsg + (size_t)i * HD * HD, m);
        k_agg<<<N_NODES / 2, 256, 0, stream>>>(m, row_start, esrc, agg);
        k_gru<<<(N_NODES + 31) / 32, 256, 0, stream>>>(agg, h, Wih, Whh, bih, bhh);
    }

    k_counts<<<(N_NODES + 255) / 256, 256, 0, stream>>>(batch, counts);
    k_pool<<<(N_NODES + POOL_CHUNK - 1) / POOL_CHUNK, 128, 0, stream>>>(h, batch, pooled);
    k_out<<<N_GRAPHS, 128, 0, stream>>>(pooled, counts, W1, b1, W2, b2, out);
}

// Round 3
// 1314.077 us; speedup vs baseline: 2.4077x; 2.4077x over previous
//
#include <hip/hip_runtime.h>
#include <hip/hip_bf16.h>
#include <math.h>

#define N_NODES 50000
#define N_EDGES 800000
#define FEAT 90
#define HD 128
#define STEPS 4
#define N_GRAPHS 100

typedef __attribute__((ext_vector_type(8))) short short8v;
typedef __attribute__((ext_vector_type(4))) float f32x4;
typedef unsigned short ushort_t;
typedef unsigned int uint_t;

__device__ __forceinline__ float sigmoid_(float x) { return 1.f / (1.f + expf(-x)); }

__device__ __forceinline__ ushort_t f2bf(float x) {
    uint_t u = __float_as_uint(x);
    uint_t r = (u + 0x7fffu + ((u >> 16) & 1u)) >> 16;   // RNE
    return (ushort_t)r;
}
__device__ __forceinline__ float bf2f(ushort_t h) { return __uint_as_float(((uint_t)h) << 16); }
__device__ __forceinline__ void splitf(float x, ushort_t& hi, ushort_t& lo) {
    hi = f2bf(x);
    lo = f2bf(x - bf2f(hi));
}

__device__ __forceinline__ f32x4 mfma16(short8v a, short8v b, f32x4 c) {
    return __builtin_amdgcn_mfma_f32_16x16x32_bf16(a, b, c, 0, 0, 0);
}

// ---------------- CSR build ----------------
__global__ void k_count(const int* __restrict__ dst, int* __restrict__ deg) {
    int e = blockIdx.x * 256 + threadIdx.x;
    if (e < N_EDGES) atomicAdd(&deg[dst[e]], 1);
}

__global__ void k_scan(const int* __restrict__ deg, int* __restrict__ row_start,
                       int* __restrict__ cursor) {
    __shared__ int sd[1024];
    __shared__ int carry_s;
    int t = threadIdx.x;
    if (t == 0) carry_s = 0;
    __syncthreads();
    for (int base = 0; base < N_NODES; base += 1024) {
        int v = base + t;
        int x = (v < N_NODES) ? deg[v] : 0;
        sd[t] = x;
        __syncthreads();
        for (int off = 1; off < 1024; off <<= 1) {
            int y = (t >= off) ? sd[t - off] : 0;
            __syncthreads();
            sd[t] += y;
            __syncthreads();
        }
        int carry = carry_s;
        int excl = carry + sd[t] - x;
        if (v < N_NODES) { row_start[v] = excl; cursor[v] = excl; }
        __syncthreads();
        if (t == 1023) carry_s = carry + sd[1023];
        __syncthreads();
    }
    if (t == 0) row_start[N_NODES] = carry_s;
}

__global__ void k_fill(const int* __restrict__ src, const int* __restrict__ dst,
                       int* __restrict__ cursor, int* __restrict__ esrc) {
    int e = blockIdx.x * 256 + threadIdx.x;
    if (e < N_EDGES) {
        int p = atomicAdd(&cursor[dst[e]], 1);
        esrc[p] = src[e];
    }
}

// ---------------- Wmi[i] = W_msg[i] @ W_ih  (f32, [4][128][384]) ----------------
__global__ __launch_bounds__(128) void k_wmi(const float* __restrict__ Wmsg,
                                             const float* __restrict__ Wih,
                                             float* __restrict__ Wmi) {
    int b = blockIdx.x;              // ((i*128)+r)*3 + cc
    int cc = b % 3;
    int ir = b / 3;
    int r = ir % 128, i = ir / 128;
    int c = cc * 128 + threadIdx.x;
    __shared__ float wrow[128];
    wrow[threadIdx.x] = Wmsg[((size_t)i * 128 + r) * 128 + threadIdx.x];
    __syncthreads();
    float acc = 0.f;
#pragma unroll 8
    for (int k = 0; k < 128; ++k) acc += wrow[k] * Wih[(size_t)k * 384 + c];
    Wmi[((size_t)i * 128 + r) * 384 + c] = acc;
}

// ---------------- pack B [128][384] f32 -> fragment-order split bf16 ----------------
// frag addressing: hi/lo[(((sl*24 + t)*64 + lane)*8 + j]
//   covers B[sl*32 + (lane>>4)*8 + j][t*16 + (lane&15)]
__global__ __launch_bounds__(256) void k_packB(const float* __restrict__ Wmi,
                                               const float* __restrict__ Whh,
                                               ushort_t* __restrict__ BmHi, ushort_t* __restrict__ BmLo,
                                               ushort_t* __restrict__ BhHi, ushort_t* __restrict__ BhLo) {
    int y = blockIdx.y;  // 0..3 -> Wmi step y ; 4 -> Whh
    const float* W;
    ushort_t *dhi, *dlo;
    if (y < 4) { W = Wmi + (size_t)y * 49152; dhi = BmHi + (size_t)y * 49152; dlo = BmLo + (size_t)y * 49152; }
    else       { W = Whh;                     dhi = BhHi;                     dlo = BhLo; }
    int g = blockIdx.x * 256 + threadIdx.x;   // 0..6143
    int lane = g & 63;
    int tt = (g >> 6) % 24;
    int sl = (g >> 6) / 24;
    int kb = sl * 32 + (lane >> 4) * 8;
    int c = tt * 16 + (lane & 15);
    short8v h8, l8;
#pragma unroll
    for (int j = 0; j < 8; ++j) {
        ushort_t hi, lo;
        splitf(W[(size_t)(kb + j) * 384 + c], hi, lo);
        h8[j] = (short)hi;
        l8[j] = (short)lo;
    }
    size_t o = (((size_t)sl * 24 + tt) * 64 + lane) * 8;
    *(short8v*)&dhi[o] = h8;
    *(short8v*)&dlo[o] = l8;
}

// ---------------- Embedding: h = relu(x @ Wemb) -> split bf16 ----------------
__global__ __launch_bounds__(256) void k_embed(const float* __restrict__ x,
                                               const float* __restrict__ Wemb,
                                               ushort_t* __restrict__ h_hi,
                                               ushort_t* __restrict__ h_lo) {
    __shared__ __align__(16) float a_s[32 * 96];
    __shared__ __align__(16) float w_s[96 * 128];
    int t = threadIdx.x;
    int n0 = blockIdx.x * 32;
    for (int i = t; i < 96 * 128; i += 256) {
        int k = i >> 7;
        w_s[i] = (k < FEAT) ? Wemb[i] : 0.f;
    }
    for (int i = t; i < 32 * 96; i += 256) {
        int r = i / 96, k = i - r * 96;
        int n = n0 + r;
        a_s[i] = (k < FEAT && n < N_NODES) ? x[(size_t)n * FEAT + k] : 0.f;
    }
    __syncthreads();
    int tx = t & 63, rg = t >> 6;
    float acc[8][2];
#pragma unroll
    for (int r = 0; r < 8; ++r) { acc[r][0] = 0.f; acc[r][1] = 0.f; }
    for (int k0 = 0; k0 < 96; k0 += 4) {
        float a4[8][4];
#pragma unroll
        for (int r = 0; r < 8; ++r)
            *(float4*)a4[r] = *(const float4*)&a_s[(rg * 8 + r) * 96 + k0];
#pragma unroll
        for (int j = 0; j < 4; ++j) {
            float w0 = w_s[(k0 + j) * 128 + tx];
            float w1 = w_s[(k0 + j) * 128 + tx + 64];
#pragma unroll
            for (int r = 0; r < 8; ++r) {
                acc[r][0] += a4[r][j] * w0;
                acc[r][1] += a4[r][j] * w1;
            }
        }
    }
#pragma unroll
    for (int r = 0; r < 8; ++r) {
        int n = n0 + rg * 8 + r;
        if (n < N_NODES) {
            float v0 = fmaxf(acc[r][0], 0.f);
            float v1 = fmaxf(acc[r][1], 0.f);
            ushort_t h0, l0, h1, l1;
            splitf(v0, h0, l0);
            splitf(v1, h1, l1);
            size_t o = (size_t)n * HD + tx;
            h_hi[o] = h0; h_lo[o] = l0;
            h_hi[o + 64] = h1; h_lo[o + 64] = l1;
        }
    }
}

// ---------------- gather: aggh[v] = sum_{e in CSR[v]} h[src_e]  (split in, split out) ----------------
__global__ __launch_bounds__(256) void k_gather(const ushort_t* __restrict__ h_hi,
                                                const ushort_t* __restrict__ h_lo,
                                                const int* __restrict__ row_start,
                                                const int* __restrict__ esrc,
                                                ushort_t* __restrict__ agg_hi,
                                                ushort_t* __restrict__ agg_lo) {
    int lane = threadIdx.x & 63;
    int wid = threadIdx.x >> 6;
    int v = blockIdx.x * 4 + wid;           // 50000 = 12500*4 exact
    int beg = row_start[v], end = row_start[v + 1];
    int off = lane * 2;
    float a0 = 0.f, a1 = 0.f;
    int j = beg;
    for (; j + 2 <= end; j += 2) {
        int s0 = esrc[j], s1 = esrc[j + 1];
        uint_t uh0 = *(const uint_t*)&h_hi[(size_t)s0 * HD + off];
        uint_t ul0 = *(const uint_t*)&h_lo[(size_t)s0 * HD + off];
        uint_t uh1 = *(const uint_t*)&h_hi[(size_t)s1 * HD + off];
        uint_t ul1 = *(const uint_t*)&h_lo[(size_t)s1 * HD + off];
        a0 += __uint_as_float(uh0 << 16) + __uint_as_float(ul0 << 16)
            + __uint_as_float(uh1 << 16) + __uint_as_float(ul1 << 16);
        a1 += __uint_as_float(uh0 & 0xffff0000u) + __uint_as_float(ul0 & 0xffff0000u)
            + __uint_as_float(uh1 & 0xffff0000u) + __uint_as_float(ul1 & 0xffff0000u);
    }
    if (j < end) {
        int s0 = esrc[j];
        uint_t uh0 = *(const uint_t*)&h_hi[(size_t)s0 * HD + off];
        uint_t ul0 = *(const uint_t*)&h_lo[(size_t)s0 * HD + off];
        a0 += __uint_as_float(uh0 << 16) + __uint_as_float(ul0 << 16);
        a1 += __uint_as_float(uh0 & 0xffff0000u) + __uint_as_float(ul0 & 0xffff0000u);
    }
    ushort_t h0, l0, h1, l1;
    splitf(a0, h0, l0);
    splitf(a1, h1, l1);
    *(uint_t*)&agg_hi[(size_t)v * HD + off] = ((uint_t)h1 << 16) | h0;
    *(uint_t*)&agg_lo[(size_t)v * HD + off] = ((uint_t)l1 << 16) | l0;
}

// ---------------- fused GRU via MFMA ----------------
// gates[N,384] = [aggh | h] @ [Wmi ; Whh], split-bf16 3-term MFMA, in-register epilogue.
// block: 256 thr = 4 waves (wr in {0,1} rows, wc in {0,1} out-col half), tile 64 rows.
__global__ __launch_bounds__(256) void k_gru_mfma(const ushort_t* __restrict__ agg_hi,
                                                  const ushort_t* __restrict__ agg_lo,
                                                  ushort_t* __restrict__ h_hi,
                                                  ushort_t* __restrict__ h_lo,
                                                  const ushort_t* __restrict__ BmHi,
                                                  const ushort_t* __restrict__ BmLo,
                                                  const ushort_t* __restrict__ BhHi,
                                                  const ushort_t* __restrict__ BhLo,
                                                  const float* __restrict__ bih,
                                                  const float* __restrict__ bhh) {
    int lane = threadIdx.x & 63;
    int wid = threadIdx.x >> 6;
    int wr = wid >> 1, wc = wid & 1;
    int row_base = blockIdx.x * 64 + wr * 32;
    int ar0 = min(row_base + (lane & 15), N_NODES - 1);
    int ar1 = min(row_base + 16 + (lane & 15), N_NODES - 1);
    int kcol = (lane >> 4) * 8;

    f32x4 accR[2][4], accZ[2][4], accXN[2][4], accHN[2][4];
#pragma unroll
    for (int rf = 0; rf < 2; ++rf)
#pragma unroll
        for (int q = 0; q < 4; ++q) {
            accR[rf][q] = (f32x4)0.f; accZ[rf][q] = (f32x4)0.f;
            accXN[rf][q] = (f32x4)0.f; accHN[rf][q] = (f32x4)0.f;
        }

#pragma unroll
    for (int s = 0; s < 8; ++s) {
        const ushort_t* Ah = (s < 4) ? agg_hi : h_hi;
        const ushort_t* Al = (s < 4) ? agg_lo : h_lo;
        const int k0 = (s & 3) * 32 + kcol;
        short8v a0h = *(const short8v*)&Ah[(size_t)ar0 * HD + k0];
        short8v a0l = *(const short8v*)&Al[(size_t)ar0 * HD + k0];
        short8v a1h = *(const short8v*)&Ah[(size_t)ar1 * HD + k0];
        short8v a1l = *(const short8v*)&Al[(size_t)ar1 * HD + k0];
        const ushort_t* Bhp = (s < 4) ? BmHi : BhHi;
        const ushort_t* Blp = (s < 4) ? BmLo : BhLo;
        const int sl = s & 3;
#pragma unroll
        for (int grp = 0; grp < 3; ++grp) {
#pragma unroll
            for (int q = 0; q < 4; ++q) {
                int tt = grp * 8 + wc * 4 + q;
                size_t bo = (((size_t)sl * 24 + tt) * 64 + lane) * 8;
                short8v bh = *(const short8v*)&Bhp[bo];
                short8v bl = *(const short8v*)&Blp[bo];
                if (grp == 0) {
                    accR[0][q] = mfma16(a0h, bh, accR[0][q]);
                    accR[0][q] = mfma16(a0h, bl, accR[0][q]);
                    accR[0][q] = mfma16(a0l, bh, accR[0][q]);
                    accR[1][q] = mfma16(a1h, bh, accR[1][q]);
                    accR[1][q] = mfma16(a1h, bl, accR[1][q]);
                    accR[1][q] = mfma16(a1l, bh, accR[1][q]);
                } else if (grp == 1) {
                    accZ[0][q] = mfma16(a0h, bh, accZ[0][q]);
                    accZ[0][q] = mfma16(a0h, bl, accZ[0][q]);
                    accZ[0][q] = mfma16(a0l, bh, accZ[0][q]);
                    accZ[1][q] = mfma16(a1h, bh, accZ[1][q]);
                    accZ[1][q] = mfma16(a1h, bl, accZ[1][q]);
                    accZ[1][q] = mfma16(a1l, bh, accZ[1][q]);
                } else if (s < 4) {
                    accXN[0][q] = mfma16(a0h, bh, accXN[0][q]);
                    accXN[0][q] = mfma16(a0h, bl, accXN[0][q]);
                    accXN[0][q] = mfma16(a0l, bh, accXN[0][q]);
                    accXN[1][q] = mfma16(a1h, bh, accXN[1][q]);
                    accXN[1][q] = mfma16(a1h, bl, accXN[1][q]);
                    accXN[1][q] = mfma16(a1l, bh, accXN[1][q]);
                } else {
                    accHN[0][q] = mfma16(a0h, bh, accHN[0][q]);
                    accHN[0][q] = mfma16(a0h, bl, accHN[0][q]);
                    accHN[0][q] = mfma16(a0l, bh, accHN[0][q]);
                    accHN[1][q] = mfma16(a1h, bh, accHN[1][q]);
                    accHN[1][q] = mfma16(a1h, bl, accHN[1][q]);
                    accHN[1][q] = mfma16(a1l, bh, accHN[1][q]);
                }
            }
        }
    }

    __syncthreads();  // all waves done reading h before anyone overwrites it

#pragma unroll
    for (int rf = 0; rf < 2; ++rf) {
#pragma unroll
        for (int q = 0; q < 4; ++q) {
            int c = wc * 64 + q * 16 + (lane & 15);
            float bir = bih[c],      bhr = bhh[c];
            float biz = bih[c + 128], bhz = bhh[c + 128];
            float bin_ = bih[c + 256], bhn = bhh[c + 256];
#pragma unroll
            for (int j = 0; j < 4; ++j) {
                int row = row_base + rf * 16 + ((lane >> 4) << 2) + j;
                if (row < N_NODES) {
                    float rr = sigmoid_(accR[rf][q][j] + bir + bhr);
                    float zz = sigmoid_(accZ[rf][q][j] + biz + bhz);
                    float nn = tanhf(accXN[rf][q][j] + bin_ + rr * (accHN[rf][q][j] + bhn));
                    size_t idx = (size_t)row * HD + c;
                    float hold = bf2f(h_hi[idx]) + bf2f(h_lo[idx]);
                    float hnew = (1.f - zz) * nn + zz * hold;
                    ushort_t hi, lo;
                    splitf(hnew, hi, lo);
                    h_hi[idx] = hi;
                    h_lo[idx] = lo;
                }
            }
        }
    }
}

// ---------------- pooling ----------------
__global__ void k_counts(const int* __restrict__ batch, int* __restrict__ counts) {
    int n = blockIdx.x * 256 + threadIdx.x;
    if (n < N_NODES) atomicAdd(&counts[batch[n]], 1);
}

#define POOL_CHUNK 256
__global__ __launch_bounds__(128) void k_pool(const ushort_t* __restrict__ h_hi,
                                              const ushort_t* __restrict__ h_lo,
                                              const int* __restrict__ batch,
                                              float* __restrict__ pooled) {
    int t = threadIdx.x;  // 128 cols
    int n0 = blockIdx.x * POOL_CHUNK;
    int nend = n0 + POOL_CHUNK;
    if (nend > N_NODES) nend = N_NODES;
    float acc = 0.f;
    int cur = batch[n0];
    for (int n = n0; n < nend; ++n) {
        int g = batch[n];
        if (g != cur) {
            atomicAdd(&pooled[(size_t)cur * HD + t], acc);
            acc = 0.f;
            cur = g;
        }
        float hv = bf2f(h_hi[(size_t)n * HD + t]) + bf2f(h_lo[(size_t)n * HD + t]);
        acc += fmaxf(hv, 0.f);  // fused final relu
    }
    atomicAdd(&pooled[(size_t)cur * HD + t], acc);
}

// ---------------- output MLP ----------------
__global__ __launch_bounds__(128) void k_out(const float* __restrict__ pooled,
                                             const int* __restrict__ counts,
                                             const float* __restrict__ W1,
                                             const float* __restrict__ b1,
                                             const float* __restrict__ W2,
                                             const float* __restrict__ b2,
                                             float* __restrict__ out) {
    __shared__ float row[128];
    __shared__ float red[128];
    int t = threadIdx.x;
    int g = blockIdx.x;
    float cnt = (float)counts[g];
    if (cnt < 1.f) cnt = 1.f;
    row[t] = pooled[(size_t)g * HD + t] / cnt;
    __syncthreads();
    float acc = b1[t];
#pragma unroll 4
    for (int k = 0; k < HD; ++k) acc += row[k] * W1[k * HD + t];
    float hv = fmaxf(acc, 0.f);
    red[t] = hv * W2[t];
    __syncthreads();
    for (int off = 64; off > 0; off >>= 1) {
        if (t < off) red[t] += red[t + off];
        __syncthreads();
    }
    if (t == 0) {
        float xv = red[0] + b2[0];
        out[g] = fmaxf(xv, 0.f) + log1pf(expf(-fabsf(xv)));
    }
}

extern "C" void kernel_launch(void* const* d_in, const int* in_sizes, int n_in,
                              void* d_out, int out_size, void* d_ws, size_t ws_size,
                              hipStream_t stream) {
    (void)in_sizes; (void)n_in; (void)out_size; (void)ws_size;
    const float* x    = (const float*)d_in[0];
    const int*   ei   = (const int*)d_in[1];
    const int*   batch= (const int*)d_in[2];
    const float* Wemb = (const float*)d_in[3];
    const float* Wmsg = (const float*)d_in[4];
    const float* Wih  = (const float*)d_in[5];
    const float* Whh  = (const float*)d_in[6];
    const float* bih  = (const float*)d_in[7];
    const float* bhh  = (const float*)d_in[8];
    const float* W1   = (const float*)d_in[9];
    const float* b1   = (const float*)d_in[10];
    const float* W2   = (const float*)d_in[11];
    const float* b2   = (const float*)d_in[12];
    float* out = (float*)d_out;

    const int* e_src = ei;
    const int* e_dst = ei + N_EDGES;

    char* ws = (char*)d_ws;
    size_t off = 0;
    auto alloc = [&](size_t bytes) -> void* {
        void* p = ws + off;
        off = (off + bytes + 255) & ~(size_t)255;
        return p;
    };
    ushort_t* h_hi   = (ushort_t*)alloc((size_t)N_NODES * HD * 2);
    ushort_t* h_lo   = (ushort_t*)alloc((size_t)N_NODES * HD * 2);
    ushort_t* agg_hi = (ushort_t*)alloc((size_t)N_NODES * HD * 2);
    ushort_t* agg_lo = (ushort_t*)alloc((size_t)N_NODES * HD * 2);
    float* Wmi       = (float*)alloc((size_t)STEPS * 128 * 384 * 4);
    ushort_t* BmHi   = (ushort_t*)alloc((size_t)STEPS * 128 * 384 * 2);
    ushort_t* BmLo   = (ushort_t*)alloc((size_t)STEPS * 128 * 384 * 2);
    ushort_t* BhHi   = (ushort_t*)alloc((size_t)128 * 384 * 2);
    ushort_t* BhLo   = (ushort_t*)alloc((size_t)128 * 384 * 2);
    float* pooled    = (float*)alloc((size_t)N_GRAPHS * HD * 4);
    int* deg         = (int*)alloc((size_t)N_NODES * 4);
    int* row_start   = (int*)alloc((size_t)(N_NODES + 1) * 4);
    int* cursor      = (int*)alloc((size_t)N_NODES * 4);
    int* esrc        = (int*)alloc((size_t)N_EDGES * 4);
    int* counts      = (int*)alloc((size_t)N_GRAPHS * 4);

    hipMemsetAsync(deg, 0, (size_t)N_NODES * 4, stream);
    hipMemsetAsync(counts, 0, (size_t)N_GRAPHS * 4, stream);
    hipMemsetAsync(pooled, 0, (size_t)N_GRAPHS * HD * 4, stream);

    k_count<<<(N_EDGES + 255) / 256, 256, 0, stream>>>(e_dst, deg);
    k_scan<<<1, 1024, 0, stream>>>(deg, row_start, cursor);
    k_fill<<<(N_EDGES + 255) / 256, 256, 0, stream>>>(e_src, e_dst, cursor, esrc);

    k_wmi<<<STEPS * 128 * 3, 128, 0, stream>>>(Wmsg, Wih, Wmi);
    k_packB<<<dim3(24, 5), 256, 0, stream>>>(Wmi, Whh, BmHi, BmLo, BhHi, BhLo);

    k_embed<<<(N_NODES + 31) / 32, 256, 0, stream>>>(x, Wemb, h_hi, h_lo);

    for (int i = 0; i < STEPS; ++i) {
        k_gather<<<N_NODES / 4, 256, 0, stream>>>(h_hi, h_lo, row_start, esrc, agg_hi, agg_lo);
        k_gru_mfma<<<(N_NODES + 63) / 64, 256, 0, stream>>>(
            agg_hi, agg_lo, h_hi, h_lo,
            BmHi + (size_t)i * 49152, BmLo + (size_t)i * 49152,
            BhHi, BhLo, bih, bhh);
    }

    k_counts<<<(N_NODES + 255) / 256, 256, 0, stream>>>(batch, counts);
    k_pool<<<(N_NODES + POOL_CHUNK - 1) / POOL_CHUNK, 128, 0, stream>>>(h_hi, h_lo, batch, pooled);
    k_out<<<N_GRAPHS, 128, 0, stream>>>(pooled, counts, W1, b1, W2, b2, out);
}

// Round 4
// 1175.980 us; speedup vs baseline: 2.6905x; 1.1174x over previous
//
#include <hip/hip_runtime.h>
#include <hip/hip_bf16.h>
#include <math.h>

#define N_NODES 50000
#define N_EDGES 800000
#define FEAT 90
#define HD 128
#define STEPS 4
#define N_GRAPHS 100

typedef __attribute__((ext_vector_type(8))) short short8v;
typedef __attribute__((ext_vector_type(8))) unsigned int uint8v;
typedef __attribute__((ext_vector_type(4))) float f32x4;
typedef unsigned short ushort_t;
typedef unsigned int uint_t;

__device__ __forceinline__ float sigmoid_(float x) { return 1.f / (1.f + expf(-x)); }

__device__ __forceinline__ ushort_t f2bf(float x) {
    uint_t u = __float_as_uint(x);
    uint_t r = (u + 0x7fffu + ((u >> 16) & 1u)) >> 16;   // RNE
    return (ushort_t)r;
}
__device__ __forceinline__ float bf2f(ushort_t h) { return __uint_as_float(((uint_t)h) << 16); }
// packed element: (hi16 << 16) | lo16 ; value = f(hi) + f(lo)
__device__ __forceinline__ uint_t packf(float x) {
    ushort_t hi = f2bf(x);
    ushort_t lo = f2bf(x - bf2f(hi));
    return ((uint_t)hi << 16) | lo;
}
__device__ __forceinline__ float unpackf(uint_t u) {
    return __uint_as_float(u & 0xffff0000u) + __uint_as_float(u << 16);
}

__device__ __forceinline__ f32x4 mfma16(short8v a, short8v b, f32x4 c) {
    return __builtin_amdgcn_mfma_f32_16x16x32_bf16(a, b, c, 0, 0, 0);
}

// ---------------- CSR build ----------------
__global__ void k_count(const int* __restrict__ dst, int* __restrict__ deg) {
    int e = blockIdx.x * 256 + threadIdx.x;
    if (e < N_EDGES) atomicAdd(&deg[dst[e]], 1);
}

// chunked scan: 1024 threads x 49 elements, one 10-step shared scan (~22 barriers)
__global__ __launch_bounds__(1024) void k_scan(const int* __restrict__ deg,
                                               int* __restrict__ row_start,
                                               int* __restrict__ cursor) {
    __shared__ int ps[1024];
    const int CH = 49;  // 1024*49 = 50176 >= 50000
    int t = threadIdx.x;
    int beg = t * CH;
    int s = 0;
    for (int i = 0; i < CH; ++i) {
        int v = beg + i;
        s += (v < N_NODES) ? deg[v] : 0;
    }
    ps[t] = s;
    __syncthreads();
    for (int off = 1; off < 1024; off <<= 1) {
        int y = (t >= off) ? ps[t - off] : 0;
        __syncthreads();
        ps[t] += y;
        __syncthreads();
    }
    int run = ps[t] - s;  // exclusive prefix of this thread's chunk
    for (int i = 0; i < CH; ++i) {
        int v = beg + i;
        if (v < N_NODES) {
            int d = deg[v];
            row_start[v] = run;
            cursor[v] = run;
            run += d;
        }
    }
    if (t == 1023) row_start[N_NODES] = run;
}

__global__ void k_fill(const int* __restrict__ src, const int* __restrict__ dst,
                       int* __restrict__ cursor, int* __restrict__ esrc) {
    int e = blockIdx.x * 256 + threadIdx.x;
    if (e < N_EDGES) {
        int p = atomicAdd(&cursor[dst[e]], 1);
        esrc[p] = src[e];
    }
}

// ---------------- Wmi[i] = W_msg[i] @ W_ih  (f32, [4][128][384]) ----------------
__global__ __launch_bounds__(128) void k_wmi(const float* __restrict__ Wmsg,
                                             const float* __restrict__ Wih,
                                             float* __restrict__ Wmi) {
    int b = blockIdx.x;              // ((i*128)+r)*3 + cc
    int cc = b % 3;
    int ir = b / 3;
    int r = ir % 128, i = ir / 128;
    int c = cc * 128 + threadIdx.x;
    __shared__ float wrow[128];
    wrow[threadIdx.x] = Wmsg[((size_t)i * 128 + r) * 128 + threadIdx.x];
    __syncthreads();
    float acc = 0.f;
#pragma unroll 8
    for (int k = 0; k < 128; ++k) acc += wrow[k] * Wih[(size_t)k * 384 + c];
    Wmi[((size_t)i * 128 + r) * 384 + c] = acc;
}

// ---------------- pack B [128][384] f32 -> fragment-order split bf16 ----------------
// frag addressing: hi/lo[(((sl*24 + t)*64 + lane)*8 + j]
//   covers B[sl*32 + (lane>>4)*8 + j][t*16 + (lane&15)]
__global__ __launch_bounds__(256) void k_packB(const float* __restrict__ Wmi,
                                               const float* __restrict__ Whh,
                                               ushort_t* __restrict__ BmHi, ushort_t* __restrict__ BmLo,
                                               ushort_t* __restrict__ BhHi, ushort_t* __restrict__ BhLo) {
    int y = blockIdx.y;  // 0..3 -> Wmi step y ; 4 -> Whh
    const float* W;
    ushort_t *dhi, *dlo;
    if (y < 4) { W = Wmi + (size_t)y * 49152; dhi = BmHi + (size_t)y * 49152; dlo = BmLo + (size_t)y * 49152; }
    else       { W = Whh;                     dhi = BhHi;                     dlo = BhLo; }
    int g = blockIdx.x * 256 + threadIdx.x;   // 0..6143
    int lane = g & 63;
    int tt = (g >> 6) % 24;
    int sl = (g >> 6) / 24;
    int kb = sl * 32 + (lane >> 4) * 8;
    int c = tt * 16 + (lane & 15);
    short8v h8, l8;
#pragma unroll
    for (int j = 0; j < 8; ++j) {
        float w = W[(size_t)(kb + j) * 384 + c];
        ushort_t hi = f2bf(w);
        ushort_t lo = f2bf(w - bf2f(hi));
        h8[j] = (short)hi;
        l8[j] = (short)lo;
    }
    size_t o = (((size_t)sl * 24 + tt) * 64 + lane) * 8;
    *(short8v*)&dhi[o] = h8;
    *(short8v*)&dlo[o] = l8;
}

// ---------------- Embedding: h = relu(x @ Wemb) -> packed split bf16 ----------------
__global__ __launch_bounds__(256) void k_embed(const float* __restrict__ x,
                                               const float* __restrict__ Wemb,
                                               uint_t* __restrict__ hp) {
    __shared__ __align__(16) float a_s[32 * 96];
    __shared__ __align__(16) float w_s[96 * 128];
    int t = threadIdx.x;
    int n0 = blockIdx.x * 32;
    for (int i = t; i < 96 * 128; i += 256) {
        int k = i >> 7;
        w_s[i] = (k < FEAT) ? Wemb[i] : 0.f;
    }
    for (int i = t; i < 32 * 96; i += 256) {
        int r = i / 96, k = i - r * 96;
        int n = n0 + r;
        a_s[i] = (k < FEAT && n < N_NODES) ? x[(size_t)n * FEAT + k] : 0.f;
    }
    __syncthreads();
    int tx = t & 63, rg = t >> 6;
    float acc[8][2];
#pragma unroll
    for (int r = 0; r < 8; ++r) { acc[r][0] = 0.f; acc[r][1] = 0.f; }
    for (int k0 = 0; k0 < 96; k0 += 4) {
        float a4[8][4];
#pragma unroll
        for (int r = 0; r < 8; ++r)
            *(float4*)a4[r] = *(const float4*)&a_s[(rg * 8 + r) * 96 + k0];
#pragma unroll
        for (int j = 0; j < 4; ++j) {
            float w0 = w_s[(k0 + j) * 128 + tx];
            float w1 = w_s[(k0 + j) * 128 + tx + 64];
#pragma unroll
            for (int r = 0; r < 8; ++r) {
                acc[r][0] += a4[r][j] * w0;
                acc[r][1] += a4[r][j] * w1;
            }
        }
    }
#pragma unroll
    for (int r = 0; r < 8; ++r) {
        int n = n0 + rg * 8 + r;
        if (n < N_NODES) {
            size_t o = (size_t)n * HD + tx;
            hp[o]      = packf(fmaxf(acc[r][0], 0.f));
            hp[o + 64] = packf(fmaxf(acc[r][1], 0.f));
        }
    }
}

// ---------------- gather: agg[v] = sum_{e in CSR[v]} h[src_e]  (packed in/out) ----------------
__global__ __launch_bounds__(256) void k_gather(const uint_t* __restrict__ hp,
                                                const int* __restrict__ row_start,
                                                const int* __restrict__ esrc,
                                                uint_t* __restrict__ aggp) {
    int lane = threadIdx.x & 63;
    int wid = threadIdx.x >> 6;
    int v = blockIdx.x * 4 + wid;           // 50000 = 12500*4 exact
    int beg = row_start[v], end = row_start[v + 1];
    int off = lane * 2;
    float a0 = 0.f, a1 = 0.f;
    int j = beg;
    for (; j + 2 <= end; j += 2) {
        int s0 = esrc[j], s1 = esrc[j + 1];
        uint2 u0 = *(const uint2*)&hp[(size_t)s0 * HD + off];
        uint2 u1 = *(const uint2*)&hp[(size_t)s1 * HD + off];
        a0 += unpackf(u0.x) + unpackf(u1.x);
        a1 += unpackf(u0.y) + unpackf(u1.y);
    }
    if (j < end) {
        uint2 u0 = *(const uint2*)&hp[(size_t)esrc[j] * HD + off];
        a0 += unpackf(u0.x);
        a1 += unpackf(u0.y);
    }
    *(uint2*)&aggp[(size_t)v * HD + off] = make_uint2(packf(a0), packf(a1));
}

// ---------------- fused GRU via MFMA ----------------
// gates[N,384] = [agg | h] @ [Wmi ; Whh], split-bf16 3-term MFMA, in-register epilogue.
// block: 256 thr = 4 waves (wr rows-half, wc out-col half), tile 64 rows.
__global__ __launch_bounds__(256) void k_gru_mfma(const uint_t* __restrict__ aggp,
                                                  uint_t* __restrict__ hp,
                                                  const ushort_t* __restrict__ BmHi,
                                                  const ushort_t* __restrict__ BmLo,
                                                  const ushort_t* __restrict__ BhHi,
                                                  const ushort_t* __restrict__ BhLo,
                                                  const float* __restrict__ bih,
                                                  const float* __restrict__ bhh) {
    int lane = threadIdx.x & 63;
    int wid = threadIdx.x >> 6;
    int wr = wid >> 1, wc = wid & 1;
    int row_base = blockIdx.x * 64 + wr * 32;
    int ar0 = min(row_base + (lane & 15), N_NODES - 1);
    int ar1 = min(row_base + 16 + (lane & 15), N_NODES - 1);
    int kcol = (lane >> 4) * 8;

    f32x4 accR[2][4], accZ[2][4], accXN[2][4], accHN[2][4];
#pragma unroll
    for (int rf = 0; rf < 2; ++rf)
#pragma unroll
        for (int q = 0; q < 4; ++q) {
            accR[rf][q] = (f32x4)0.f; accZ[rf][q] = (f32x4)0.f;
            accXN[rf][q] = (f32x4)0.f; accHN[rf][q] = (f32x4)0.f;
        }

#pragma unroll
    for (int s = 0; s < 8; ++s) {
        const uint_t* Ap = (s < 4) ? aggp : hp;
        const int k0 = (s & 3) * 32 + kcol;
        uint8v u0 = *(const uint8v*)&Ap[(size_t)ar0 * HD + k0];
        uint8v u1 = *(const uint8v*)&Ap[(size_t)ar1 * HD + k0];
        short8v a0h, a0l, a1h, a1l;
#pragma unroll
        for (int j = 0; j < 8; ++j) {
            a0h[j] = (short)(u0[j] >> 16); a0l[j] = (short)(u0[j] & 0xffffu);
            a1h[j] = (short)(u1[j] >> 16); a1l[j] = (short)(u1[j] & 0xffffu);
        }
        const ushort_t* Bhp = (s < 4) ? BmHi : BhHi;
        const ushort_t* Blp = (s < 4) ? BmLo : BhLo;
        const int sl = s & 3;
#pragma unroll
        for (int grp = 0; grp < 3; ++grp) {
#pragma unroll
            for (int q = 0; q < 4; ++q) {
                int tt = grp * 8 + wc * 4 + q;
                size_t bo = (((size_t)sl * 24 + tt) * 64 + lane) * 8;
                short8v bh = *(const short8v*)&Bhp[bo];
                short8v bl = *(const short8v*)&Blp[bo];
                if (grp == 0) {
                    accR[0][q] = mfma16(a0h, bh, accR[0][q]);
                    accR[0][q] = mfma16(a0h, bl, accR[0][q]);
                    accR[0][q] = mfma16(a0l, bh, accR[0][q]);
                    accR[1][q] = mfma16(a1h, bh, accR[1][q]);
                    accR[1][q] = mfma16(a1h, bl, accR[1][q]);
                    accR[1][q] = mfma16(a1l, bh, accR[1][q]);
                } else if (grp == 1) {
                    accZ[0][q] = mfma16(a0h, bh, accZ[0][q]);
                    accZ[0][q] = mfma16(a0h, bl, accZ[0][q]);
                    accZ[0][q] = mfma16(a0l, bh, accZ[0][q]);
                    accZ[1][q] = mfma16(a1h, bh, accZ[1][q]);
                    accZ[1][q] = mfma16(a1h, bl, accZ[1][q]);
                    accZ[1][q] = mfma16(a1l, bh, accZ[1][q]);
                } else if (s < 4) {
                    accXN[0][q] = mfma16(a0h, bh, accXN[0][q]);
                    accXN[0][q] = mfma16(a0h, bl, accXN[0][q]);
                    accXN[0][q] = mfma16(a0l, bh, accXN[0][q]);
                    accXN[1][q] = mfma16(a1h, bh, accXN[1][q]);
                    accXN[1][q] = mfma16(a1h, bl, accXN[1][q]);
                    accXN[1][q] = mfma16(a1l, bh, accXN[1][q]);
                } else {
                    accHN[0][q] = mfma16(a0h, bh, accHN[0][q]);
                    accHN[0][q] = mfma16(a0h, bl, accHN[0][q]);
                    accHN[0][q] = mfma16(a0l, bh, accHN[0][q]);
                    accHN[1][q] = mfma16(a1h, bh, accHN[1][q]);
                    accHN[1][q] = mfma16(a1h, bl, accHN[1][q]);
                    accHN[1][q] = mfma16(a1l, bh, accHN[1][q]);
                }
            }
        }
    }

    __syncthreads();  // all waves done reading h before anyone overwrites it

#pragma unroll
    for (int rf = 0; rf < 2; ++rf) {
#pragma unroll
        for (int q = 0; q < 4; ++q) {
            int c = wc * 64 + q * 16 + (lane & 15);
            float bir = bih[c],       bhr = bhh[c];
            float biz = bih[c + 128], bhz = bhh[c + 128];
            float bin_ = bih[c + 256], bhn = bhh[c + 256];
#pragma unroll
            for (int j = 0; j < 4; ++j) {
                int row = row_base + rf * 16 + ((lane >> 4) << 2) + j;
                if (row < N_NODES) {
                    float rr = sigmoid_(accR[rf][q][j] + bir + bhr);
                    float zz = sigmoid_(accZ[rf][q][j] + biz + bhz);
                    float nn = tanhf(accXN[rf][q][j] + bin_ + rr * (accHN[rf][q][j] + bhn));
                    size_t idx = (size_t)row * HD + c;
                    float hold = unpackf(hp[idx]);
                    hp[idx] = packf((1.f - zz) * nn + zz * hold);
                }
            }
        }
    }
}

// ---------------- pooling ----------------
#define POOL_CHUNK 256
__global__ __launch_bounds__(128) void k_pool(const uint_t* __restrict__ hp,
                                              const int* __restrict__ batch,
                                              float* __restrict__ pooled) {
    int t = threadIdx.x;  // 128 cols
    int n0 = blockIdx.x * POOL_CHUNK;
    int nend = n0 + POOL_CHUNK;
    if (nend > N_NODES) nend = N_NODES;
    float acc = 0.f;
    int cur = batch[n0];
    for (int n = n0; n < nend; ++n) {
        int g = batch[n];
        if (g != cur) {
            atomicAdd(&pooled[(size_t)cur * HD + t], acc);
            acc = 0.f;
            cur = g;
        }
        acc += fmaxf(unpackf(hp[(size_t)n * HD + t]), 0.f);  // fused final relu
    }
    atomicAdd(&pooled[(size_t)cur * HD + t], acc);
}

// ---------------- output MLP (counts via binary search on sorted batch) ----------------
__global__ __launch_bounds__(128) void k_out(const float* __restrict__ pooled,
                                             const int* __restrict__ batch,
                                             const float* __restrict__ W1,
                                             const float* __restrict__ b1,
                                             const float* __restrict__ W2,
                                             const float* __restrict__ b2,
                                             float* __restrict__ out) {
    __shared__ float row[128];
    __shared__ float red[128];
    int t = threadIdx.x;
    int g = blockIdx.x;
    // lower_bound(batch, g) and lower_bound(batch, g+1)
    int lo0 = 0, hi0 = N_NODES;
    while (lo0 < hi0) { int mid = (lo0 + hi0) >> 1; if (batch[mid] < g) lo0 = mid + 1; else hi0 = mid; }
    int lo1 = lo0, hi1 = N_NODES;
    while (lo1 < hi1) { int mid = (lo1 + hi1) >> 1; if (batch[mid] < g + 1) lo1 = mid + 1; else hi1 = mid; }
    float cnt = (float)(lo1 - lo0);
    if (cnt < 1.f) cnt = 1.f;
    row[t] = pooled[(size_t)g * HD + t] / cnt;
    __syncthreads();
    float acc = b1[t];
#pragma unroll 4
    for (int k = 0; k < HD; ++k) acc += row[k] * W1[k * HD + t];
    float hv = fmaxf(acc, 0.f);
    red[t] = hv * W2[t];
    __syncthreads();
    for (int off = 64; off > 0; off >>= 1) {
        if (t < off) red[t] += red[t + off];
        __syncthreads();
    }
    if (t == 0) {
        float xv = red[0] + b2[0];
        out[g] = fmaxf(xv, 0.f) + log1pf(expf(-fabsf(xv)));
    }
}

extern "C" void kernel_launch(void* const* d_in, const int* in_sizes, int n_in,
                              void* d_out, int out_size, void* d_ws, size_t ws_size,
                              hipStream_t stream) {
    (void)in_sizes; (void)n_in; (void)out_size; (void)ws_size;
    const float* x    = (const float*)d_in[0];
    const int*   ei   = (const int*)d_in[1];
    const int*   batch= (const int*)d_in[2];
    const float* Wemb = (const float*)d_in[3];
    const float* Wmsg = (const float*)d_in[4];
    const float* Wih  = (const float*)d_in[5];
    const float* Whh  = (const float*)d_in[6];
    const float* bih  = (const float*)d_in[7];
    const float* bhh  = (const float*)d_in[8];
    const float* W1   = (const float*)d_in[9];
    const float* b1   = (const float*)d_in[10];
    const float* W2   = (const float*)d_in[11];
    const float* b2   = (const float*)d_in[12];
    float* out = (float*)d_out;

    const int* e_src = ei;
    const int* e_dst = ei + N_EDGES;

    char* ws = (char*)d_ws;
    size_t off = 0;
    auto alloc = [&](size_t bytes) -> void* {
        void* p = ws + off;
        off = (off + bytes + 255) & ~(size_t)255;
        return p;
    };
    uint_t* hp       = (uint_t*)alloc((size_t)N_NODES * HD * 4);
    uint_t* aggp     = (uint_t*)alloc((size_t)N_NODES * HD * 4);
    float* Wmi       = (float*)alloc((size_t)STEPS * 128 * 384 * 4);
    ushort_t* BmHi   = (ushort_t*)alloc((size_t)STEPS * 128 * 384 * 2);
    ushort_t* BmLo   = (ushort_t*)alloc((size_t)STEPS * 128 * 384 * 2);
    ushort_t* BhHi   = (ushort_t*)alloc((size_t)128 * 384 * 2);
    ushort_t* BhLo   = (ushort_t*)alloc((size_t)128 * 384 * 2);
    float* pooled    = (float*)alloc((size_t)N_GRAPHS * HD * 4);
    int* deg         = (int*)alloc((size_t)N_NODES * 4);
    int* row_start   = (int*)alloc((size_t)(N_NODES + 1) * 4);
    int* cursor      = (int*)alloc((size_t)N_NODES * 4);
    int* esrc        = (int*)alloc((size_t)N_EDGES * 4);

    hipMemsetAsync(deg, 0, (size_t)N_NODES * 4, stream);
    hipMemsetAsync(pooled, 0, (size_t)N_GRAPHS * HD * 4, stream);

    k_count<<<(N_EDGES + 255) / 256, 256, 0, stream>>>(e_dst, deg);
    k_scan<<<1, 1024, 0, stream>>>(deg, row_start, cursor);
    k_fill<<<(N_EDGES + 255) / 256, 256, 0, stream>>>(e_src, e_dst, cursor, esrc);

    k_wmi<<<STEPS * 128 * 3, 128, 0, stream>>>(Wmsg, Wih, Wmi);
    k_packB<<<dim3(24, 5), 256, 0, stream>>>(Wmi, Whh, BmHi, BmLo, BhHi, BhLo);

    k_embed<<<(N_NODES + 31) / 32, 256, 0, stream>>>(x, Wemb, hp);

    for (int i = 0; i < STEPS; ++i) {
        k_gather<<<N_NODES / 4, 256, 0, stream>>>(hp, row_start, esrc, aggp);
        k_gru_mfma<<<(N_NODES + 63) / 64, 256, 0, stream>>>(
            aggp, hp,
            BmHi + (size_t)i * 49152, BmLo + (size_t)i * 49152,
            BhHi, BhLo, bih, bhh);
    }

    k_pool<<<(N_NODES + POOL_CHUNK - 1) / POOL_CHUNK, 128, 0, stream>>>(hp, batch, pooled);
    k_out<<<N_GRAPHS, 128, 0, stream>>>(pooled, batch, W1, b1, W2, b2, out);
}

// Round 5
// 1049.773 us; speedup vs baseline: 3.0139x; 1.1202x over previous
//
#include <hip/hip_runtime.h>
#include <hip/hip_bf16.h>
#include <math.h>

#define N_NODES 50000
#define N_EDGES 800000
#define FEAT 90
#define HD 128
#define STEPS 4
#define N_GRAPHS 100

typedef __attribute__((ext_vector_type(8))) short short8v;
typedef __attribute__((ext_vector_type(8))) unsigned int uint8v;
typedef __attribute__((ext_vector_type(4))) float f32x4;
typedef unsigned short ushort_t;
typedef unsigned int uint_t;

__device__ __forceinline__ float sigmoid_(float x) { return 1.f / (1.f + expf(-x)); }

__device__ __forceinline__ ushort_t f2bf(float x) {
    uint_t u = __float_as_uint(x);
    uint_t r = (u + 0x7fffu + ((u >> 16) & 1u)) >> 16;   // RNE
    return (ushort_t)r;
}
__device__ __forceinline__ float bf2f(ushort_t h) { return __uint_as_float(((uint_t)h) << 16); }
// packed element: (hi16 << 16) | lo16 ; value = f(hi) + f(lo)
__device__ __forceinline__ uint_t packf(float x) {
    ushort_t hi = f2bf(x);
    ushort_t lo = f2bf(x - bf2f(hi));
    return ((uint_t)hi << 16) | lo;
}
__device__ __forceinline__ float unpackf(uint_t u) {
    return __uint_as_float(u & 0xffff0000u) + __uint_as_float(u << 16);
}

__device__ __forceinline__ f32x4 mfma16(short8v a, short8v b, f32x4 c) {
    return __builtin_amdgcn_mfma_f32_16x16x32_bf16(a, b, c, 0, 0, 0);
}

// ---------------- CSR build ----------------
__global__ void k_count(const int* __restrict__ dst, int* __restrict__ deg) {
    int e = blockIdx.x * 256 + threadIdx.x;
    if (e < N_EDGES) atomicAdd(&deg[dst[e]], 1);
}

// chunked scan: 1024 threads x 49 elements, one 10-step shared scan
__global__ __launch_bounds__(1024) void k_scan(const int* __restrict__ deg,
                                               int* __restrict__ row_start,
                                               int* __restrict__ cursor) {
    __shared__ int ps[1024];
    const int CH = 49;  // 1024*49 = 50176 >= 50000
    int t = threadIdx.x;
    int beg = t * CH;
    int s = 0;
    for (int i = 0; i < CH; ++i) {
        int v = beg + i;
        s += (v < N_NODES) ? deg[v] : 0;
    }
    ps[t] = s;
    __syncthreads();
    for (int off = 1; off < 1024; off <<= 1) {
        int y = (t >= off) ? ps[t - off] : 0;
        __syncthreads();
        ps[t] += y;
        __syncthreads();
    }
    int run = ps[t] - s;  // exclusive prefix of this thread's chunk
    for (int i = 0; i < CH; ++i) {
        int v = beg + i;
        if (v < N_NODES) {
            int d = deg[v];
            row_start[v] = run;
            cursor[v] = run;
            run += d;
        }
    }
    if (t == 1023) row_start[N_NODES] = run;
}

__global__ void k_fill(const int* __restrict__ src, const int* __restrict__ dst,
                       int* __restrict__ cursor, int* __restrict__ esrc) {
    int e = blockIdx.x * 256 + threadIdx.x;
    if (e < N_EDGES) {
        int p = atomicAdd(&cursor[dst[e]], 1);
        esrc[p] = src[e];
    }
}

// ---------------- Wmi[i] = W_msg[i] @ W_ih  (f32, [4][128][384]) ----------------
__global__ __launch_bounds__(128) void k_wmi(const float* __restrict__ Wmsg,
                                             const float* __restrict__ Wih,
                                             float* __restrict__ Wmi) {
    int b = blockIdx.x;              // ((i*128)+r)*3 + cc
    int cc = b % 3;
    int ir = b / 3;
    int r = ir % 128, i = ir / 128;
    int c = cc * 128 + threadIdx.x;
    __shared__ float wrow[128];
    wrow[threadIdx.x] = Wmsg[((size_t)i * 128 + r) * 128 + threadIdx.x];
    __syncthreads();
    float acc = 0.f;
#pragma unroll 8
    for (int k = 0; k < 128; ++k) acc += wrow[k] * Wih[(size_t)k * 384 + c];
    Wmi[((size_t)i * 128 + r) * 384 + c] = acc;
}

// ---------------- pack B [128][384] f32 -> fragment-order split bf16 ----------------
// frag addressing: hi/lo[(((sl*24 + t)*64 + lane)*8 + j]
//   covers B[sl*32 + (lane>>4)*8 + j][t*16 + (lane&15)]
__global__ __launch_bounds__(256) void k_packB(const float* __restrict__ Wmi,
                                               const float* __restrict__ Whh,
                                               ushort_t* __restrict__ BmHi, ushort_t* __restrict__ BmLo,
                                               ushort_t* __restrict__ BhHi, ushort_t* __restrict__ BhLo) {
    int y = blockIdx.y;  // 0..3 -> Wmi step y ; 4 -> Whh
    const float* W;
    ushort_t *dhi, *dlo;
    if (y < 4) { W = Wmi + (size_t)y * 49152; dhi = BmHi + (size_t)y * 49152; dlo = BmLo + (size_t)y * 49152; }
    else       { W = Whh;                     dhi = BhHi;                     dlo = BhLo; }
    int g = blockIdx.x * 256 + threadIdx.x;   // 0..6143
    int lane = g & 63;
    int tt = (g >> 6) % 24;
    int sl = (g >> 6) / 24;
    int kb = sl * 32 + (lane >> 4) * 8;
    int c = tt * 16 + (lane & 15);
    short8v h8, l8;
#pragma unroll
    for (int j = 0; j < 8; ++j) {
        float w = W[(size_t)(kb + j) * 384 + c];
        ushort_t hi = f2bf(w);
        ushort_t lo = f2bf(w - bf2f(hi));
        h8[j] = (short)hi;
        l8[j] = (short)lo;
    }
    size_t o = (((size_t)sl * 24 + tt) * 64 + lane) * 8;
    *(short8v*)&dhi[o] = h8;
    *(short8v*)&dlo[o] = l8;
}

// ---------------- Embedding: h = relu(x @ Wemb) -> packed split bf16 ----------------
__global__ __launch_bounds__(256) void k_embed(const float* __restrict__ x,
                                               const float* __restrict__ Wemb,
                                               uint_t* __restrict__ hp) {
    __shared__ __align__(16) float a_s[32 * 96];
    __shared__ __align__(16) float w_s[96 * 128];
    int t = threadIdx.x;
    int n0 = blockIdx.x * 32;
    for (int i = t; i < 96 * 128; i += 256) {
        int k = i >> 7;
        w_s[i] = (k < FEAT) ? Wemb[i] : 0.f;
    }
    for (int i = t; i < 32 * 96; i += 256) {
        int r = i / 96, k = i - r * 96;
        int n = n0 + r;
        a_s[i] = (k < FEAT && n < N_NODES) ? x[(size_t)n * FEAT + k] : 0.f;
    }
    __syncthreads();
    int tx = t & 63, rg = t >> 6;
    float acc[8][2];
#pragma unroll
    for (int r = 0; r < 8; ++r) { acc[r][0] = 0.f; acc[r][1] = 0.f; }
    for (int k0 = 0; k0 < 96; k0 += 4) {
        float a4[8][4];
#pragma unroll
        for (int r = 0; r < 8; ++r)
            *(float4*)a4[r] = *(const float4*)&a_s[(rg * 8 + r) * 96 + k0];
#pragma unroll
        for (int j = 0; j < 4; ++j) {
            float w0 = w_s[(k0 + j) * 128 + tx];
            float w1 = w_s[(k0 + j) * 128 + tx + 64];
#pragma unroll
            for (int r = 0; r < 8; ++r) {
                acc[r][0] += a4[r][j] * w0;
                acc[r][1] += a4[r][j] * w1;
            }
        }
    }
#pragma unroll
    for (int r = 0; r < 8; ++r) {
        int n = n0 + rg * 8 + r;
        if (n < N_NODES) {
            size_t o = (size_t)n * HD + tx;
            hp[o]      = packf(fmaxf(acc[r][0], 0.f));
            hp[o + 64] = packf(fmaxf(acc[r][1], 0.f));
        }
    }
}

// ---------------- gather: agg[v] = sum_{e in CSR[v]} h[src_e]  (packed in/out) ----------------
__global__ __launch_bounds__(256) void k_gather(const uint_t* __restrict__ hp,
                                                const int* __restrict__ row_start,
                                                const int* __restrict__ esrc,
                                                uint_t* __restrict__ aggp) {
    int lane = threadIdx.x & 63;
    int wid = threadIdx.x >> 6;
    int v = blockIdx.x * 4 + wid;           // 50000 = 12500*4 exact
    int beg = row_start[v], end = row_start[v + 1];
    int off = lane * 2;
    float a0 = 0.f, a1 = 0.f;
    int j = beg;
    for (; j + 2 <= end; j += 2) {
        int s0 = esrc[j], s1 = esrc[j + 1];
        uint2 u0 = *(const uint2*)&hp[(size_t)s0 * HD + off];
        uint2 u1 = *(const uint2*)&hp[(size_t)s1 * HD + off];
        a0 += unpackf(u0.x) + unpackf(u1.x);
        a1 += unpackf(u0.y) + unpackf(u1.y);
    }
    if (j < end) {
        uint2 u0 = *(const uint2*)&hp[(size_t)esrc[j] * HD + off];
        a0 += unpackf(u0.x);
        a1 += unpackf(u0.y);
    }
    *(uint2*)&aggp[(size_t)v * HD + off] = make_uint2(packf(a0), packf(a1));
}

// ---------------- fused GRU via MFMA, LDS-staged B ----------------
// gates[N,384] = [agg | h] @ [Wmi ; Whh], split-bf16 3-term MFMA, in-register epilogue.
// block: 256 thr = 4 waves (wr rows-half, wc out-col half), tile 64 rows.
// B fragments staged per (source, k-slice) stage into 48KB LDS (3 blocks/CU).
__global__ __launch_bounds__(256, 3) void k_gru_mfma(const uint_t* __restrict__ aggp,
                                                     uint_t* __restrict__ hp,
                                                     const ushort_t* __restrict__ BmHi,
                                                     const ushort_t* __restrict__ BmLo,
                                                     const ushort_t* __restrict__ BhHi,
                                                     const ushort_t* __restrict__ BhLo,
                                                     const float* __restrict__ bih,
                                                     const float* __restrict__ bhh) {
    __shared__ __align__(16) ushort_t bsm[24576];  // [hi:12288][lo:12288], each [tt][lane][8]
    int t = threadIdx.x;
    int lane = t & 63;
    int wid = t >> 6;
    int wr = wid >> 1, wc = wid & 1;
    int row_base = blockIdx.x * 64 + wr * 32;
    int ar0 = min(row_base + (lane & 15), N_NODES - 1);
    int ar1 = min(row_base + 16 + (lane & 15), N_NODES - 1);
    int kcol = (lane >> 4) * 8;

    f32x4 accR[2][4], accZ[2][4], accXN[2][4], accHN[2][4];
#pragma unroll
    for (int rf = 0; rf < 2; ++rf)
#pragma unroll
        for (int q = 0; q < 4; ++q) {
            accR[rf][q] = (f32x4)0.f; accZ[rf][q] = (f32x4)0.f;
            accXN[rf][q] = (f32x4)0.f; accHN[rf][q] = (f32x4)0.f;
        }

#pragma unroll
    for (int src = 0; src < 2; ++src) {
        const uint_t* Ap = src ? hp : aggp;
        const ushort_t* BH = src ? BhHi : BmHi;
        const ushort_t* BL = src ? BhLo : BmLo;
#pragma unroll
        for (int sl = 0; sl < 4; ++sl) {
            // A fragment loads (issued early; latency hidden behind staging+barrier)
            const int k0 = sl * 32 + kcol;
            uint8v u0 = *(const uint8v*)&Ap[(size_t)ar0 * HD + k0];
            uint8v u1 = *(const uint8v*)&Ap[(size_t)ar1 * HD + k0];
            // cooperative stage of this (src, sl) B slice: 1536+1536 uint4 chunks
            {
                const uint4* gh = (const uint4*)(BH + (size_t)sl * 12288);
                const uint4* gl = (const uint4*)(BL + (size_t)sl * 12288);
                uint4* sh = (uint4*)bsm;
                uint4* slo = (uint4*)(bsm + 12288);
#pragma unroll
                for (int i = 0; i < 6; ++i) {
                    uint4 vh = gh[t + i * 256];
                    uint4 vl = gl[t + i * 256];
                    sh[t + i * 256] = vh;
                    slo[t + i * 256] = vl;
                }
            }
            __syncthreads();
            short8v a0h, a0l, a1h, a1l;
#pragma unroll
            for (int j = 0; j < 8; ++j) {
                a0h[j] = (short)(u0[j] >> 16); a0l[j] = (short)(u0[j] & 0xffffu);
                a1h[j] = (short)(u1[j] >> 16); a1l[j] = (short)(u1[j] & 0xffffu);
            }
#pragma unroll
            for (int grp = 0; grp < 3; ++grp) {
#pragma unroll
                for (int q = 0; q < 4; ++q) {
                    int tt = grp * 8 + wc * 4 + q;
                    int fo = (tt * 64 + lane) * 8;
                    short8v bh = *(const short8v*)&bsm[fo];
                    short8v bl = *(const short8v*)&bsm[12288 + fo];
                    if (grp == 0) {
                        accR[0][q] = mfma16(a0h, bh, accR[0][q]);
                        accR[0][q] = mfma16(a0h, bl, accR[0][q]);
                        accR[0][q] = mfma16(a0l, bh, accR[0][q]);
                        accR[1][q] = mfma16(a1h, bh, accR[1][q]);
                        accR[1][q] = mfma16(a1h, bl, accR[1][q]);
                        accR[1][q] = mfma16(a1l, bh, accR[1][q]);
                    } else if (grp == 1) {
                        accZ[0][q] = mfma16(a0h, bh, accZ[0][q]);
                        accZ[0][q] = mfma16(a0h, bl, accZ[0][q]);
                        accZ[0][q] = mfma16(a0l, bh, accZ[0][q]);
                        accZ[1][q] = mfma16(a1h, bh, accZ[1][q]);
                        accZ[1][q] = mfma16(a1h, bl, accZ[1][q]);
                        accZ[1][q] = mfma16(a1l, bh, accZ[1][q]);
                    } else if (src == 0) {
                        accXN[0][q] = mfma16(a0h, bh, accXN[0][q]);
                        accXN[0][q] = mfma16(a0h, bl, accXN[0][q]);
                        accXN[0][q] = mfma16(a0l, bh, accXN[0][q]);
                        accXN[1][q] = mfma16(a1h, bh, accXN[1][q]);
                        accXN[1][q] = mfma16(a1h, bl, accXN[1][q]);
                        accXN[1][q] = mfma16(a1l, bh, accXN[1][q]);
                    } else {
                        accHN[0][q] = mfma16(a0h, bh, accHN[0][q]);
                        accHN[0][q] = mfma16(a0h, bl, accHN[0][q]);
                        accHN[0][q] = mfma16(a0l, bh, accHN[0][q]);
                        accHN[1][q] = mfma16(a1h, bh, accHN[1][q]);
                        accHN[1][q] = mfma16(a1h, bl, accHN[1][q]);
                        accHN[1][q] = mfma16(a1l, bh, accHN[1][q]);
                    }
                }
            }
            __syncthreads();  // also guarantees (via vmcnt drain) h-reads done before epilogue writes
        }
    }

#pragma unroll
    for (int rf = 0; rf < 2; ++rf) {
#pragma unroll
        for (int q = 0; q < 4; ++q) {
            int c = wc * 64 + q * 16 + (lane & 15);
            float bir = bih[c],       bhr = bhh[c];
            float biz = bih[c + 128], bhz = bhh[c + 128];
            float bin_ = bih[c + 256], bhn = bhh[c + 256];
#pragma unroll
            for (int j = 0; j < 4; ++j) {
                int row = row_base + rf * 16 + ((lane >> 4) << 2) + j;
                if (row < N_NODES) {
                    float rr = sigmoid_(accR[rf][q][j] + bir + bhr);
                    float zz = sigmoid_(accZ[rf][q][j] + biz + bhz);
                    float nn = tanhf(accXN[rf][q][j] + bin_ + rr * (accHN[rf][q][j] + bhn));
                    size_t idx = (size_t)row * HD + c;
                    float hold = unpackf(hp[idx]);
                    hp[idx] = packf((1.f - zz) * nn + zz * hold);
                }
            }
        }
    }
}

// ---------------- pooling ----------------
#define POOL_CHUNK 256
__global__ __launch_bounds__(128) void k_pool(const uint_t* __restrict__ hp,
                                              const int* __restrict__ batch,
                                              float* __restrict__ pooled) {
    int t = threadIdx.x;  // 128 cols
    int n0 = blockIdx.x * POOL_CHUNK;
    int nend = n0 + POOL_CHUNK;
    if (nend > N_NODES) nend = N_NODES;
    float acc = 0.f;
    int cur = batch[n0];
    for (int n = n0; n < nend; ++n) {
        int g = batch[n];
        if (g != cur) {
            atomicAdd(&pooled[(size_t)cur * HD + t], acc);
            acc = 0.f;
            cur = g;
        }
        acc += fmaxf(unpackf(hp[(size_t)n * HD + t]), 0.f);  // fused final relu
    }
    atomicAdd(&pooled[(size_t)cur * HD + t], acc);
}

// ---------------- output MLP (counts via binary search on sorted batch) ----------------
__global__ __launch_bounds__(128) void k_out(const float* __restrict__ pooled,
                                             const int* __restrict__ batch,
                                             const float* __restrict__ W1,
                                             const float* __restrict__ b1,
                                             const float* __restrict__ W2,
                                             const float* __restrict__ b2,
                                             float* __restrict__ out) {
    __shared__ float row[128];
    __shared__ float red[128];
    int t = threadIdx.x;
    int g = blockIdx.x;
    int lo0 = 0, hi0 = N_NODES;
    while (lo0 < hi0) { int mid = (lo0 + hi0) >> 1; if (batch[mid] < g) lo0 = mid + 1; else hi0 = mid; }
    int lo1 = lo0, hi1 = N_NODES;
    while (lo1 < hi1) { int mid = (lo1 + hi1) >> 1; if (batch[mid] < g + 1) lo1 = mid + 1; else hi1 = mid; }
    float cnt = (float)(lo1 - lo0);
    if (cnt < 1.f) cnt = 1.f;
    row[t] = pooled[(size_t)g * HD + t] / cnt;
    __syncthreads();
    float acc = b1[t];
#pragma unroll 4
    for (int k = 0; k < HD; ++k) acc += row[k] * W1[k * HD + t];
    float hv = fmaxf(acc, 0.f);
    red[t] = hv * W2[t];
    __syncthreads();
    for (int off = 64; off > 0; off >>= 1) {
        if (t < off) red[t] += red[t + off];
        __syncthreads();
    }
    if (t == 0) {
        float xv = red[0] + b2[0];
        out[g] = fmaxf(xv, 0.f) + log1pf(expf(-fabsf(xv)));
    }
}

extern "C" void kernel_launch(void* const* d_in, const int* in_sizes, int n_in,
                              void* d_out, int out_size, void* d_ws, size_t ws_size,
                              hipStream_t stream) {
    (void)in_sizes; (void)n_in; (void)out_size; (void)ws_size;
    const float* x    = (const float*)d_in[0];
    const int*   ei   = (const int*)d_in[1];
    const int*   batch= (const int*)d_in[2];
    const float* Wemb = (const float*)d_in[3];
    const float* Wmsg = (const float*)d_in[4];
    const float* Wih  = (const float*)d_in[5];
    const float* Whh  = (const float*)d_in[6];
    const float* bih  = (const float*)d_in[7];
    const float* bhh  = (const float*)d_in[8];
    const float* W1   = (const float*)d_in[9];
    const float* b1   = (const float*)d_in[10];
    const float* W2   = (const float*)d_in[11];
    const float* b2   = (const float*)d_in[12];
    float* out = (float*)d_out;

    const int* e_src = ei;
    const int* e_dst = ei + N_EDGES;

    char* ws = (char*)d_ws;
    size_t off = 0;
    auto alloc = [&](size_t bytes) -> void* {
        void* p = ws + off;
        off = (off + bytes + 255) & ~(size_t)255;
        return p;
    };
    uint_t* hp       = (uint_t*)alloc((size_t)N_NODES * HD * 4);
    uint_t* aggp     = (uint_t*)alloc((size_t)N_NODES * HD * 4);
    float* Wmi       = (float*)alloc((size_t)STEPS * 128 * 384 * 4);
    ushort_t* BmHi   = (ushort_t*)alloc((size_t)STEPS * 128 * 384 * 2);
    ushort_t* BmLo   = (ushort_t*)alloc((size_t)STEPS * 128 * 384 * 2);
    ushort_t* BhHi   = (ushort_t*)alloc((size_t)128 * 384 * 2);
    ushort_t* BhLo   = (ushort_t*)alloc((size_t)128 * 384 * 2);
    float* pooled    = (float*)alloc((size_t)N_GRAPHS * HD * 4);
    int* deg         = (int*)alloc((size_t)N_NODES * 4);
    int* row_start   = (int*)alloc((size_t)(N_NODES + 1) * 4);
    int* cursor      = (int*)alloc((size_t)N_NODES * 4);
    int* esrc        = (int*)alloc((size_t)N_EDGES * 4);

    hipMemsetAsync(deg, 0, (size_t)N_NODES * 4, stream);
    hipMemsetAsync(pooled, 0, (size_t)N_GRAPHS * HD * 4, stream);

    k_count<<<(N_EDGES + 255) / 256, 256, 0, stream>>>(e_dst, deg);
    k_scan<<<1, 1024, 0, stream>>>(deg, row_start, cursor);
    k_fill<<<(N_EDGES + 255) / 256, 256, 0, stream>>>(e_src, e_dst, cursor, esrc);

    k_wmi<<<STEPS * 128 * 3, 128, 0, stream>>>(Wmsg, Wih, Wmi);
    k_packB<<<dim3(24, 5), 256, 0, stream>>>(Wmi, Whh, BmHi, BmLo, BhHi, BhLo);

    k_embed<<<(N_NODES + 31) / 32, 256, 0, stream>>>(x, Wemb, hp);

    for (int i = 0; i < STEPS; ++i) {
        k_gather<<<N_NODES / 4, 256, 0, stream>>>(hp, row_start, esrc, aggp);
        k_gru_mfma<<<(N_NODES + 63) / 64, 256, 0, stream>>>(
            aggp, hp,
            BmHi + (size_t)i * 49152, BmLo + (size_t)i * 49152,
            BhHi, BhLo, bih, bhh);
    }

    k_pool<<<(N_NODES + POOL_CHUNK - 1) / POOL_CHUNK, 128, 0, stream>>>(hp, batch, pooled);
    k_out<<<N_GRAPHS, 128, 0, stream>>>(pooled, batch, W1, b1, W2, b2, out);
}

// Round 6
// 913.330 us; speedup vs baseline: 3.4642x; 1.1494x over previous
//
#include <hip/hip_runtime.h>
#include <hip/hip_bf16.h>
#include <math.h>

#define N_NODES 50000
#define N_EDGES 800000
#define FEAT 90
#define HD 128
#define STEPS 4
#define N_GRAPHS 100
#define SCAN_BLOCKS 196  // 196*256 = 50176 >= 50000

typedef __attribute__((ext_vector_type(8))) short short8v;
typedef __attribute__((ext_vector_type(8))) unsigned int uint8v;
typedef __attribute__((ext_vector_type(4))) float f32x4;
typedef unsigned short ushort_t;
typedef unsigned int uint_t;

__device__ __forceinline__ float sigmoid_(float x) { return 1.f / (1.f + expf(-x)); }

__device__ __forceinline__ ushort_t f2bf(float x) {
    uint_t u = __float_as_uint(x);
    uint_t r = (u + 0x7fffu + ((u >> 16) & 1u)) >> 16;   // RNE
    return (ushort_t)r;
}
__device__ __forceinline__ float bf2f(ushort_t h) { return __uint_as_float(((uint_t)h) << 16); }
// packed element: (hi16 << 16) | lo16 ; value = f(hi) + f(lo)
__device__ __forceinline__ uint_t packf(float x) {
    ushort_t hi = f2bf(x);
    ushort_t lo = f2bf(x - bf2f(hi));
    return ((uint_t)hi << 16) | lo;
}
__device__ __forceinline__ float unpackf(uint_t u) {
    return __uint_as_float(u & 0xffff0000u) + __uint_as_float(u << 16);
}

__device__ __forceinline__ f32x4 mfma16(short8v a, short8v b, f32x4 c) {
    return __builtin_amdgcn_mfma_f32_16x16x32_bf16(a, b, c, 0, 0, 0);
}

// ---------------- CSR build ----------------
__global__ void k_count(const int* __restrict__ dst, int* __restrict__ deg) {
    int e = blockIdx.x * 256 + threadIdx.x;
    if (e < N_EDGES) atomicAdd(&deg[dst[e]], 1);
}

// phase 1: per-block sums of deg (coalesced)
__global__ __launch_bounds__(256) void k_bsum(const int* __restrict__ deg,
                                              int* __restrict__ bsum) {
    int t = threadIdx.x, b = blockIdx.x;
    int v = b * 256 + t;
    int x = (v < N_NODES) ? deg[v] : 0;
#pragma unroll
    for (int off = 32; off > 0; off >>= 1) x += __shfl_down(x, off, 64);
    __shared__ int ws[4];
    if ((t & 63) == 0) ws[t >> 6] = x;
    __syncthreads();
    if (t == 0) bsum[b] = ws[0] + ws[1] + ws[2] + ws[3];
}

// phase 2: exclusive scan of the 196 block sums (single tiny block)
__global__ __launch_bounds__(256) void k_bscan(const int* __restrict__ bsum,
                                               int* __restrict__ bpre) {
    __shared__ int s[256];
    int t = threadIdx.x;
    int x = (t < SCAN_BLOCKS) ? bsum[t] : 0;
    s[t] = x;
    __syncthreads();
    for (int off = 1; off < 256; off <<= 1) {
        int y = (t >= off) ? s[t - off] : 0;
        __syncthreads();
        s[t] += y;
        __syncthreads();
    }
    if (t < SCAN_BLOCKS) bpre[t] = s[t] - x;
}

// phase 3: per-block 256-wide scan + block prefix, coalesced writes
__global__ __launch_bounds__(256) void k_wscan(const int* __restrict__ deg,
                                               const int* __restrict__ bpre,
                                               int* __restrict__ row_start,
                                               int* __restrict__ cursor) {
    __shared__ int s[256];
    int t = threadIdx.x, b = blockIdx.x;
    int v = b * 256 + t;
    int x = (v < N_NODES) ? deg[v] : 0;
    s[t] = x;
    __syncthreads();
    for (int off = 1; off < 256; off <<= 1) {
        int y = (t >= off) ? s[t - off] : 0;
        __syncthreads();
        s[t] += y;
        __syncthreads();
    }
    int excl = bpre[b] + s[t] - x;
    if (v < N_NODES) { row_start[v] = excl; cursor[v] = excl; }
    if (b == 0 && t == 0) row_start[N_NODES] = N_EDGES;  // all dst are valid nodes
}

__global__ void k_fill(const int* __restrict__ src, const int* __restrict__ dst,
                       int* __restrict__ cursor, int* __restrict__ esrc) {
    int e = blockIdx.x * 256 + threadIdx.x;
    if (e < N_EDGES) {
        int p = atomicAdd(&cursor[dst[e]], 1);
        esrc[p] = src[e];
    }
}

// ---------------- Wmi[i] = W_msg[i] @ W_ih  (f32, [4][128][384]) ----------------
__global__ __launch_bounds__(128) void k_wmi(const float* __restrict__ Wmsg,
                                             const float* __restrict__ Wih,
                                             float* __restrict__ Wmi) {
    int b = blockIdx.x;              // ((i*128)+r)*3 + cc
    int cc = b % 3;
    int ir = b / 3;
    int r = ir % 128, i = ir / 128;
    int c = cc * 128 + threadIdx.x;
    __shared__ float wrow[128];
    wrow[threadIdx.x] = Wmsg[((size_t)i * 128 + r) * 128 + threadIdx.x];
    __syncthreads();
    float acc = 0.f;
#pragma unroll 8
    for (int k = 0; k < 128; ++k) acc += wrow[k] * Wih[(size_t)k * 384 + c];
    Wmi[((size_t)i * 128 + r) * 384 + c] = acc;
}

// ---------------- pack B [128][384] f32 -> fragment-order split bf16 ----------------
// frag addressing: hi/lo[(((sl*24 + t)*64 + lane)*8 + j]
//   covers B[sl*32 + (lane>>4)*8 + j][t*16 + (lane&15)]
__global__ __launch_bounds__(256) void k_packB(const float* __restrict__ Wmi,
                                               const float* __restrict__ Whh,
                                               ushort_t* __restrict__ BmHi, ushort_t* __restrict__ BmLo,
                                               ushort_t* __restrict__ BhHi, ushort_t* __restrict__ BhLo) {
    int y = blockIdx.y;  // 0..3 -> Wmi step y ; 4 -> Whh
    const float* W;
    ushort_t *dhi, *dlo;
    if (y < 4) { W = Wmi + (size_t)y * 49152; dhi = BmHi + (size_t)y * 49152; dlo = BmLo + (size_t)y * 49152; }
    else       { W = Whh;                     dhi = BhHi;                     dlo = BhLo; }
    int g = blockIdx.x * 256 + threadIdx.x;   // 0..6143
    int lane = g & 63;
    int tt = (g >> 6) % 24;
    int sl = (g >> 6) / 24;
    int kb = sl * 32 + (lane >> 4) * 8;
    int c = tt * 16 + (lane & 15);
    short8v h8, l8;
#pragma unroll
    for (int j = 0; j < 8; ++j) {
        float w = W[(size_t)(kb + j) * 384 + c];
        ushort_t hi = f2bf(w);
        ushort_t lo = f2bf(w - bf2f(hi));
        h8[j] = (short)hi;
        l8[j] = (short)lo;
    }
    size_t o = (((size_t)sl * 24 + tt) * 64 + lane) * 8;
    *(short8v*)&dhi[o] = h8;
    *(short8v*)&dlo[o] = l8;
}

// ---------------- Embedding: h = relu(x @ Wemb) -> packed split bf16 ----------------
__global__ __launch_bounds__(256) void k_embed(const float* __restrict__ x,
                                               const float* __restrict__ Wemb,
                                               uint_t* __restrict__ hp) {
    __shared__ __align__(16) float a_s[32 * 96];
    __shared__ __align__(16) float w_s[96 * 128];
    int t = threadIdx.x;
    int n0 = blockIdx.x * 32;
    for (int i = t; i < 96 * 128; i += 256) {
        int k = i >> 7;
        w_s[i] = (k < FEAT) ? Wemb[i] : 0.f;
    }
    for (int i = t; i < 32 * 96; i += 256) {
        int r = i / 96, k = i - r * 96;
        int n = n0 + r;
        a_s[i] = (k < FEAT && n < N_NODES) ? x[(size_t)n * FEAT + k] : 0.f;
    }
    __syncthreads();
    int tx = t & 63, rg = t >> 6;
    float acc[8][2];
#pragma unroll
    for (int r = 0; r < 8; ++r) { acc[r][0] = 0.f; acc[r][1] = 0.f; }
    for (int k0 = 0; k0 < 96; k0 += 4) {
        float a4[8][4];
#pragma unroll
        for (int r = 0; r < 8; ++r)
            *(float4*)a4[r] = *(const float4*)&a_s[(rg * 8 + r) * 96 + k0];
#pragma unroll
        for (int j = 0; j < 4; ++j) {
            float w0 = w_s[(k0 + j) * 128 + tx];
            float w1 = w_s[(k0 + j) * 128 + tx + 64];
#pragma unroll
            for (int r = 0; r < 8; ++r) {
                acc[r][0] += a4[r][j] * w0;
                acc[r][1] += a4[r][j] * w1;
            }
        }
    }
#pragma unroll
    for (int r = 0; r < 8; ++r) {
        int n = n0 + rg * 8 + r;
        if (n < N_NODES) {
            size_t o = (size_t)n * HD + tx;
            hp[o]      = packf(fmaxf(acc[r][0], 0.f));
            hp[o + 64] = packf(fmaxf(acc[r][1], 0.f));
        }
    }
}

// ---------------- gather: agg[v] = sum_{e in CSR[v]} h[src_e]  (packed in/out) ----------------
__global__ __launch_bounds__(256) void k_gather(const uint_t* __restrict__ hp,
                                                const int* __restrict__ row_start,
                                                const int* __restrict__ esrc,
                                                uint_t* __restrict__ aggp) {
    int lane = threadIdx.x & 63;
    int wid = threadIdx.x >> 6;
    int v = blockIdx.x * 4 + wid;           // 50000 = 12500*4 exact
    int beg = row_start[v], end = row_start[v + 1];
    int off = lane * 2;
    float a0 = 0.f, a1 = 0.f;
    int j = beg;
    for (; j + 4 <= end; j += 4) {
        int s0 = esrc[j], s1 = esrc[j + 1], s2 = esrc[j + 2], s3 = esrc[j + 3];
        uint2 u0 = *(const uint2*)&hp[(size_t)s0 * HD + off];
        uint2 u1 = *(const uint2*)&hp[(size_t)s1 * HD + off];
        uint2 u2 = *(const uint2*)&hp[(size_t)s2 * HD + off];
        uint2 u3 = *(const uint2*)&hp[(size_t)s3 * HD + off];
        a0 += unpackf(u0.x) + unpackf(u1.x) + unpackf(u2.x) + unpackf(u3.x);
        a1 += unpackf(u0.y) + unpackf(u1.y) + unpackf(u2.y) + unpackf(u3.y);
    }
    for (; j + 2 <= end; j += 2) {
        int s0 = esrc[j], s1 = esrc[j + 1];
        uint2 u0 = *(const uint2*)&hp[(size_t)s0 * HD + off];
        uint2 u1 = *(const uint2*)&hp[(size_t)s1 * HD + off];
        a0 += unpackf(u0.x) + unpackf(u1.x);
        a1 += unpackf(u0.y) + unpackf(u1.y);
    }
    if (j < end) {
        uint2 u0 = *(const uint2*)&hp[(size_t)esrc[j] * HD + off];
        a0 += unpackf(u0.x);
        a1 += unpackf(u0.y);
    }
    *(uint2*)&aggp[(size_t)v * HD + off] = make_uint2(packf(a0), packf(a1));
}

// ---------------- fused GRU via MFMA, LDS-staged B ----------------
// gates[N,384] = [agg | h] @ [Wmi ; Whh], split-bf16 3-term MFMA, in-register epilogue.
// block: 256 thr = 4 waves (wr rows-half, wc out-col half), tile 64 rows.
// B fragments staged per (source, k-slice) stage into 48KB LDS (3 blocks/CU).
__global__ __launch_bounds__(256, 3) void k_gru_mfma(const uint_t* __restrict__ aggp,
                                                     uint_t* __restrict__ hp,
                                                     const ushort_t* __restrict__ BmHi,
                                                     const ushort_t* __restrict__ BmLo,
                                                     const ushort_t* __restrict__ BhHi,
                                                     const ushort_t* __restrict__ BhLo,
                                                     const float* __restrict__ bih,
                                                     const float* __restrict__ bhh) {
    __shared__ __align__(16) ushort_t bsm[24576];  // [hi:12288][lo:12288], each [tt][lane][8]
    int t = threadIdx.x;
    int lane = t & 63;
    int wid = t >> 6;
    int wr = wid >> 1, wc = wid & 1;
    int row_base = blockIdx.x * 64 + wr * 32;
    int ar0 = min(row_base + (lane & 15), N_NODES - 1);
    int ar1 = min(row_base + 16 + (lane & 15), N_NODES - 1);
    int kcol = (lane >> 4) * 8;

    f32x4 accR[2][4], accZ[2][4], accXN[2][4], accHN[2][4];
#pragma unroll
    for (int rf = 0; rf < 2; ++rf)
#pragma unroll
        for (int q = 0; q < 4; ++q) {
            accR[rf][q] = (f32x4)0.f; accZ[rf][q] = (f32x4)0.f;
            accXN[rf][q] = (f32x4)0.f; accHN[rf][q] = (f32x4)0.f;
        }

#pragma unroll
    for (int src = 0; src < 2; ++src) {
        const uint_t* Ap = src ? hp : aggp;
        const ushort_t* BH = src ? BhHi : BmHi;
        const ushort_t* BL = src ? BhLo : BmLo;
#pragma unroll
        for (int sl = 0; sl < 4; ++sl) {
            // A fragment loads (issued early; latency hidden behind staging+barrier)
            const int k0 = sl * 32 + kcol;
            uint8v u0 = *(const uint8v*)&Ap[(size_t)ar0 * HD + k0];
            uint8v u1 = *(const uint8v*)&Ap[(size_t)ar1 * HD + k0];
            // cooperative stage of this (src, sl) B slice: 1536+1536 uint4 chunks
            {
                const uint4* gh = (const uint4*)(BH + (size_t)sl * 12288);
                const uint4* gl = (const uint4*)(BL + (size_t)sl * 12288);
                uint4* sh = (uint4*)bsm;
                uint4* slo = (uint4*)(bsm + 12288);
#pragma unroll
                for (int i = 0; i < 6; ++i) {
                    uint4 vh = gh[t + i * 256];
                    uint4 vl = gl[t + i * 256];
                    sh[t + i * 256] = vh;
                    slo[t + i * 256] = vl;
                }
            }
            __syncthreads();
            short8v a0h, a0l, a1h, a1l;
#pragma unroll
            for (int j = 0; j < 8; ++j) {
                a0h[j] = (short)(u0[j] >> 16); a0l[j] = (short)(u0[j] & 0xffffu);
                a1h[j] = (short)(u1[j] >> 16); a1l[j] = (short)(u1[j] & 0xffffu);
            }
#pragma unroll
            for (int grp = 0; grp < 3; ++grp) {
#pragma unroll
                for (int q = 0; q < 4; ++q) {
                    int tt = grp * 8 + wc * 4 + q;
                    int fo = (tt * 64 + lane) * 8;
                    short8v bh = *(const short8v*)&bsm[fo];
                    short8v bl = *(const short8v*)&bsm[12288 + fo];
                    if (grp == 0) {
                        accR[0][q] = mfma16(a0h, bh, accR[0][q]);
                        accR[0][q] = mfma16(a0h, bl, accR[0][q]);
                        accR[0][q] = mfma16(a0l, bh, accR[0][q]);
                        accR[1][q] = mfma16(a1h, bh, accR[1][q]);
                        accR[1][q] = mfma16(a1h, bl, accR[1][q]);
                        accR[1][q] = mfma16(a1l, bh, accR[1][q]);
                    } else if (grp == 1) {
                        accZ[0][q] = mfma16(a0h, bh, accZ[0][q]);
                        accZ[0][q] = mfma16(a0h, bl, accZ[0][q]);
                        accZ[0][q] = mfma16(a0l, bh, accZ[0][q]);
                        accZ[1][q] = mfma16(a1h, bh, accZ[1][q]);
                        accZ[1][q] = mfma16(a1h, bl, accZ[1][q]);
                        accZ[1][q] = mfma16(a1l, bh, accZ[1][q]);
                    } else if (src == 0) {
                        accXN[0][q] = mfma16(a0h, bh, accXN[0][q]);
                        accXN[0][q] = mfma16(a0h, bl, accXN[0][q]);
                        accXN[0][q] = mfma16(a0l, bh, accXN[0][q]);
                        accXN[1][q] = mfma16(a1h, bh, accXN[1][q]);
                        accXN[1][q] = mfma16(a1h, bl, accXN[1][q]);
                        accXN[1][q] = mfma16(a1l, bh, accXN[1][q]);
                    } else {
                        accHN[0][q] = mfma16(a0h, bh, accHN[0][q]);
                        accHN[0][q] = mfma16(a0h, bl, accHN[0][q]);
                        accHN[0][q] = mfma16(a0l, bh, accHN[0][q]);
                        accHN[1][q] = mfma16(a1h, bh, accHN[1][q]);
                        accHN[1][q] = mfma16(a1h, bl, accHN[1][q]);
                        accHN[1][q] = mfma16(a1l, bh, accHN[1][q]);
                    }
                }
            }
            __syncthreads();
        }
    }

#pragma unroll
    for (int rf = 0; rf < 2; ++rf) {
#pragma unroll
        for (int q = 0; q < 4; ++q) {
            int c = wc * 64 + q * 16 + (lane & 15);
            float bir = bih[c],       bhr = bhh[c];
            float biz = bih[c + 128], bhz = bhh[c + 128];
            float bin_ = bih[c + 256], bhn = bhh[c + 256];
#pragma unroll
            for (int j = 0; j < 4; ++j) {
                int row = row_base + rf * 16 + ((lane >> 4) << 2) + j;
                if (row < N_NODES) {
                    float rr = sigmoid_(accR[rf][q][j] + bir + bhr);
                    float zz = sigmoid_(accZ[rf][q][j] + biz + bhz);
                    float nn = tanhf(accXN[rf][q][j] + bin_ + rr * (accHN[rf][q][j] + bhn));
                    size_t idx = (size_t)row * HD + c;
                    float hold = unpackf(hp[idx]);
                    hp[idx] = packf((1.f - zz) * nn + zz * hold);
                }
            }
        }
    }
}

// ---------------- pooling ----------------
#define POOL_CHUNK 256
__global__ __launch_bounds__(128) void k_pool(const uint_t* __restrict__ hp,
                                              const int* __restrict__ batch,
                                              float* __restrict__ pooled) {
    int t = threadIdx.x;  // 128 cols
    int n0 = blockIdx.x * POOL_CHUNK;
    int nend = n0 + POOL_CHUNK;
    if (nend > N_NODES) nend = N_NODES;
    float acc = 0.f;
    int cur = batch[n0];
    for (int n = n0; n < nend; ++n) {
        int g = batch[n];
        if (g != cur) {
            atomicAdd(&pooled[(size_t)cur * HD + t], acc);
            acc = 0.f;
            cur = g;
        }
        acc += fmaxf(unpackf(hp[(size_t)n * HD + t]), 0.f);  // fused final relu
    }
    atomicAdd(&pooled[(size_t)cur * HD + t], acc);
}

// ---------------- output MLP (counts via binary search on sorted batch) ----------------
__global__ __launch_bounds__(128) void k_out(const float* __restrict__ pooled,
                                             const int* __restrict__ batch,
                                             const float* __restrict__ W1,
                                             const float* __restrict__ b1,
                                             const float* __restrict__ W2,
                                             const float* __restrict__ b2,
                                             float* __restrict__ out) {
    __shared__ float row[128];
    __shared__ float red[128];
    int t = threadIdx.x;
    int g = blockIdx.x;
    int lo0 = 0, hi0 = N_NODES;
    while (lo0 < hi0) { int mid = (lo0 + hi0) >> 1; if (batch[mid] < g) lo0 = mid + 1; else hi0 = mid; }
    int lo1 = lo0, hi1 = N_NODES;
    while (lo1 < hi1) { int mid = (lo1 + hi1) >> 1; if (batch[mid] < g + 1) lo1 = mid + 1; else hi1 = mid; }
    float cnt = (float)(lo1 - lo0);
    if (cnt < 1.f) cnt = 1.f;
    row[t] = pooled[(size_t)g * HD + t] / cnt;
    __syncthreads();
    float acc = b1[t];
#pragma unroll 4
    for (int k = 0; k < HD; ++k) acc += row[k] * W1[k * HD + t];
    float hv = fmaxf(acc, 0.f);
    red[t] = hv * W2[t];
    __syncthreads();
    for (int off = 64; off > 0; off >>= 1) {
        if (t < off) red[t] += red[t + off];
        __syncthreads();
    }
    if (t == 0) {
        float xv = red[0] + b2[0];
        out[g] = fmaxf(xv, 0.f) + log1pf(expf(-fabsf(xv)));
    }
}

extern "C" void kernel_launch(void* const* d_in, const int* in_sizes, int n_in,
                              void* d_out, int out_size, void* d_ws, size_t ws_size,
                              hipStream_t stream) {
    (void)in_sizes; (void)n_in; (void)out_size; (void)ws_size;
    const float* x    = (const float*)d_in[0];
    const int*   ei   = (const int*)d_in[1];
    const int*   batch= (const int*)d_in[2];
    const float* Wemb = (const float*)d_in[3];
    const float* Wmsg = (const float*)d_in[4];
    const float* Wih  = (const float*)d_in[5];
    const float* Whh  = (const float*)d_in[6];
    const float* bih  = (const float*)d_in[7];
    const float* bhh  = (const float*)d_in[8];
    const float* W1   = (const float*)d_in[9];
    const float* b1   = (const float*)d_in[10];
    const float* W2   = (const float*)d_in[11];
    const float* b2   = (const float*)d_in[12];
    float* out = (float*)d_out;

    const int* e_src = ei;
    const int* e_dst = ei + N_EDGES;

    char* ws = (char*)d_ws;
    size_t off = 0;
    auto alloc = [&](size_t bytes) -> void* {
        void* p = ws + off;
        off = (off + bytes + 255) & ~(size_t)255;
        return p;
    };
    uint_t* hp       = (uint_t*)alloc((size_t)N_NODES * HD * 4);
    uint_t* aggp     = (uint_t*)alloc((size_t)N_NODES * HD * 4);
    float* Wmi       = (float*)alloc((size_t)STEPS * 128 * 384 * 4);
    ushort_t* BmHi   = (ushort_t*)alloc((size_t)STEPS * 128 * 384 * 2);
    ushort_t* BmLo   = (ushort_t*)alloc((size_t)STEPS * 128 * 384 * 2);
    ushort_t* BhHi   = (ushort_t*)alloc((size_t)128 * 384 * 2);
    ushort_t* BhLo   = (ushort_t*)alloc((size_t)128 * 384 * 2);
    float* pooled    = (float*)alloc((size_t)N_GRAPHS * HD * 4);
    int* deg         = (int*)alloc((size_t)N_NODES * 4);
    int* row_start   = (int*)alloc((size_t)(N_NODES + 1) * 4);
    int* cursor      = (int*)alloc((size_t)N_NODES * 4);
    int* esrc        = (int*)alloc((size_t)N_EDGES * 4);
    int* bsum        = (int*)alloc((size_t)SCAN_BLOCKS * 4);
    int* bpre        = (int*)alloc((size_t)SCAN_BLOCKS * 4);

    hipMemsetAsync(deg, 0, (size_t)N_NODES * 4, stream);
    hipMemsetAsync(pooled, 0, (size_t)N_GRAPHS * HD * 4, stream);

    k_count<<<(N_EDGES + 255) / 256, 256, 0, stream>>>(e_dst, deg);
    k_bsum<<<SCAN_BLOCKS, 256, 0, stream>>>(deg, bsum);
    k_bscan<<<1, 256, 0, stream>>>(bsum, bpre);
    k_wscan<<<SCAN_BLOCKS, 256, 0, stream>>>(deg, bpre, row_start, cursor);
    k_fill<<<(N_EDGES + 255) / 256, 256, 0, stream>>>(e_src, e_dst, cursor, esrc);

    k_wmi<<<STEPS * 128 * 3, 128, 0, stream>>>(Wmsg, Wih, Wmi);
    k_packB<<<dim3(24, 5), 256, 0, stream>>>(Wmi, Whh, BmHi, BmLo, BhHi, BhLo);

    k_embed<<<(N_NODES + 31) / 32, 256, 0, stream>>>(x, Wemb, hp);

    for (int i = 0; i < STEPS; ++i) {
        k_gather<<<N_NODES / 4, 256, 0, stream>>>(hp, row_start, esrc, aggp);
        k_gru_mfma<<<(N_NODES + 63) / 64, 256, 0, stream>>>(
            aggp, hp,
            BmHi + (size_t)i * 49152, BmLo + (size_t)i * 49152,
            BhHi, BhLo, bih, bhh);
    }

    k_pool<<<(N_NODES + POOL_CHUNK - 1) / POOL_CHUNK, 128, 0, stream>>>(hp, batch, pooled);
    k_out<<<N_GRAPHS, 128, 0, stream>>>(pooled, batch, W1, b1, W2, b2, out);
}

// Round 7
// 897.911 us; speedup vs baseline: 3.5237x; 1.0172x over previous
//
#include <hip/hip_runtime.h>
#include <hip/hip_bf16.h>
#include <math.h>

#define N_NODES 50000
#define N_EDGES 800000
#define FEAT 90
#define HD 128
#define STEPS 4
#define N_GRAPHS 100
#define SCAN_BLOCKS 196  // 196*256 = 50176 >= 50000
#define GRU_ROWS 128

typedef __attribute__((ext_vector_type(8))) short short8v;
typedef __attribute__((ext_vector_type(8))) unsigned int uint8v;
typedef __attribute__((ext_vector_type(4))) float f32x4;
typedef unsigned short ushort_t;
typedef unsigned int uint_t;

__device__ __forceinline__ float sigmoid_(float x) { return 1.f / (1.f + expf(-x)); }

__device__ __forceinline__ ushort_t f2bf(float x) {
    uint_t u = __float_as_uint(x);
    uint_t r = (u + 0x7fffu + ((u >> 16) & 1u)) >> 16;   // RNE
    return (ushort_t)r;
}
__device__ __forceinline__ float bf2f(ushort_t h) { return __uint_as_float(((uint_t)h) << 16); }
// packed element: (hi16 << 16) | lo16 ; value = f(hi) + f(lo)
__device__ __forceinline__ uint_t packf(float x) {
    ushort_t hi = f2bf(x);
    ushort_t lo = f2bf(x - bf2f(hi));
    return ((uint_t)hi << 16) | lo;
}
__device__ __forceinline__ float unpackf(uint_t u) {
    return __uint_as_float(u & 0xffff0000u) + __uint_as_float(u << 16);
}

__device__ __forceinline__ f32x4 mfma16(short8v a, short8v b, f32x4 c) {
    return __builtin_amdgcn_mfma_f32_16x16x32_bf16(a, b, c, 0, 0, 0);
}

// ---------------- CSR build ----------------
__global__ void k_count(const int* __restrict__ dst, int* __restrict__ deg) {
    int e = blockIdx.x * 256 + threadIdx.x;
    if (e < N_EDGES) atomicAdd(&deg[dst[e]], 1);
}

// phase 1: per-block sums of deg (coalesced)
__global__ __launch_bounds__(256) void k_bsum(const int* __restrict__ deg,
                                              int* __restrict__ bsum) {
    int t = threadIdx.x, b = blockIdx.x;
    int v = b * 256 + t;
    int x = (v < N_NODES) ? deg[v] : 0;
#pragma unroll
    for (int off = 32; off > 0; off >>= 1) x += __shfl_down(x, off, 64);
    __shared__ int ws[4];
    if ((t & 63) == 0) ws[t >> 6] = x;
    __syncthreads();
    if (t == 0) bsum[b] = ws[0] + ws[1] + ws[2] + ws[3];
}

// phase 2: exclusive scan of the 196 block sums (single tiny block)
__global__ __launch_bounds__(256) void k_bscan(const int* __restrict__ bsum,
                                               int* __restrict__ bpre) {
    __shared__ int s[256];
    int t = threadIdx.x;
    int x = (t < SCAN_BLOCKS) ? bsum[t] : 0;
    s[t] = x;
    __syncthreads();
    for (int off = 1; off < 256; off <<= 1) {
        int y = (t >= off) ? s[t - off] : 0;
        __syncthreads();
        s[t] += y;
        __syncthreads();
    }
    if (t < SCAN_BLOCKS) bpre[t] = s[t] - x;
}

// phase 3: per-block 256-wide scan + block prefix, coalesced writes
__global__ __launch_bounds__(256) void k_wscan(const int* __restrict__ deg,
                                               const int* __restrict__ bpre,
                                               int* __restrict__ row_start,
                                               int* __restrict__ cursor) {
    __shared__ int s[256];
    int t = threadIdx.x, b = blockIdx.x;
    int v = b * 256 + t;
    int x = (v < N_NODES) ? deg[v] : 0;
    s[t] = x;
    __syncthreads();
    for (int off = 1; off < 256; off <<= 1) {
        int y = (t >= off) ? s[t - off] : 0;
        __syncthreads();
        s[t] += y;
        __syncthreads();
    }
    int excl = bpre[b] + s[t] - x;
    if (v < N_NODES) { row_start[v] = excl; cursor[v] = excl; }
    if (b == 0 && t == 0) row_start[N_NODES] = N_EDGES;  // all dst are valid nodes
}

__global__ void k_fill(const int* __restrict__ src, const int* __restrict__ dst,
                       int* __restrict__ cursor, int* __restrict__ esrc) {
    int e = blockIdx.x * 256 + threadIdx.x;
    if (e < N_EDGES) {
        int p = atomicAdd(&cursor[dst[e]], 1);
        esrc[p] = src[e];
    }
}

// ---------------- Wmi[i] = W_msg[i] @ W_ih  (f32, [4][128][384]) ----------------
__global__ __launch_bounds__(128) void k_wmi(const float* __restrict__ Wmsg,
                                             const float* __restrict__ Wih,
                                             float* __restrict__ Wmi) {
    int b = blockIdx.x;              // ((i*128)+r)*3 + cc
    int cc = b % 3;
    int ir = b / 3;
    int r = ir % 128, i = ir / 128;
    int c = cc * 128 + threadIdx.x;
    __shared__ float wrow[128];
    wrow[threadIdx.x] = Wmsg[((size_t)i * 128 + r) * 128 + threadIdx.x];
    __syncthreads();
    float acc = 0.f;
#pragma unroll 8
    for (int k = 0; k < 128; ++k) acc += wrow[k] * Wih[(size_t)k * 384 + c];
    Wmi[((size_t)i * 128 + r) * 384 + c] = acc;
}

// ---------------- pack B [128][384] f32 -> fragment-order split bf16 ----------------
// frag addressing: hi/lo[(((sl*24 + t)*64 + lane)*8 + j]
//   covers B[sl*32 + (lane>>4)*8 + j][t*16 + (lane&15)]
__global__ __launch_bounds__(256) void k_packB(const float* __restrict__ Wmi,
                                               const float* __restrict__ Whh,
                                               ushort_t* __restrict__ BmHi, ushort_t* __restrict__ BmLo,
                                               ushort_t* __restrict__ BhHi, ushort_t* __restrict__ BhLo) {
    int y = blockIdx.y;  // 0..3 -> Wmi step y ; 4 -> Whh
    const float* W;
    ushort_t *dhi, *dlo;
    if (y < 4) { W = Wmi + (size_t)y * 49152; dhi = BmHi + (size_t)y * 49152; dlo = BmLo + (size_t)y * 49152; }
    else       { W = Whh;                     dhi = BhHi;                     dlo = BhLo; }
    int g = blockIdx.x * 256 + threadIdx.x;   // 0..6143
    int lane = g & 63;
    int tt = (g >> 6) % 24;
    int sl = (g >> 6) / 24;
    int kb = sl * 32 + (lane >> 4) * 8;
    int c = tt * 16 + (lane & 15);
    short8v h8, l8;
#pragma unroll
    for (int j = 0; j < 8; ++j) {
        float w = W[(size_t)(kb + j) * 384 + c];
        ushort_t hi = f2bf(w);
        ushort_t lo = f2bf(w - bf2f(hi));
        h8[j] = (short)hi;
        l8[j] = (short)lo;
    }
    size_t o = (((size_t)sl * 24 + tt) * 64 + lane) * 8;
    *(short8v*)&dhi[o] = h8;
    *(short8v*)&dlo[o] = l8;
}

// ---------------- Embedding: h = relu(x @ Wemb) -> packed split bf16 ----------------
__global__ __launch_bounds__(256) void k_embed(const float* __restrict__ x,
                                               const float* __restrict__ Wemb,
                                               uint_t* __restrict__ hp) {
    __shared__ __align__(16) float a_s[32 * 96];
    __shared__ __align__(16) float w_s[96 * 128];
    int t = threadIdx.x;
    int n0 = blockIdx.x * 32;
    for (int i = t; i < 96 * 128; i += 256) {
        int k = i >> 7;
        w_s[i] = (k < FEAT) ? Wemb[i] : 0.f;
    }
    for (int i = t; i < 32 * 96; i += 256) {
        int r = i / 96, k = i - r * 96;
        int n = n0 + r;
        a_s[i] = (k < FEAT && n < N_NODES) ? x[(size_t)n * FEAT + k] : 0.f;
    }
    __syncthreads();
    int tx = t & 63, rg = t >> 6;
    float acc[8][2];
#pragma unroll
    for (int r = 0; r < 8; ++r) { acc[r][0] = 0.f; acc[r][1] = 0.f; }
    for (int k0 = 0; k0 < 96; k0 += 4) {
        float a4[8][4];
#pragma unroll
        for (int r = 0; r < 8; ++r)
            *(float4*)a4[r] = *(const float4*)&a_s[(rg * 8 + r) * 96 + k0];
#pragma unroll
        for (int j = 0; j < 4; ++j) {
            float w0 = w_s[(k0 + j) * 128 + tx];
            float w1 = w_s[(k0 + j) * 128 + tx + 64];
#pragma unroll
            for (int r = 0; r < 8; ++r) {
                acc[r][0] += a4[r][j] * w0;
                acc[r][1] += a4[r][j] * w1;
            }
        }
    }
#pragma unroll
    for (int r = 0; r < 8; ++r) {
        int n = n0 + rg * 8 + r;
        if (n < N_NODES) {
            size_t o = (size_t)n * HD + tx;
            hp[o]      = packf(fmaxf(acc[r][0], 0.f));
            hp[o + 64] = packf(fmaxf(acc[r][1], 0.f));
        }
    }
}

// ---------------- gather: agg[v] = sum_{e in CSR[v]} h[src_e]  (packed in/out) ----------------
__global__ __launch_bounds__(256) void k_gather(const uint_t* __restrict__ hp,
                                                const int* __restrict__ row_start,
                                                const int* __restrict__ esrc,
                                                uint_t* __restrict__ aggp) {
    int lane = threadIdx.x & 63;
    int wid = threadIdx.x >> 6;
    int v = blockIdx.x * 4 + wid;           // 50000 = 12500*4 exact
    int beg = row_start[v], end = row_start[v + 1];
    int off = lane * 2;
    float a0 = 0.f, a1 = 0.f;
    int j = beg;
    for (; j + 4 <= end; j += 4) {
        int s0 = esrc[j], s1 = esrc[j + 1], s2 = esrc[j + 2], s3 = esrc[j + 3];
        uint2 u0 = *(const uint2*)&hp[(size_t)s0 * HD + off];
        uint2 u1 = *(const uint2*)&hp[(size_t)s1 * HD + off];
        uint2 u2 = *(const uint2*)&hp[(size_t)s2 * HD + off];
        uint2 u3 = *(const uint2*)&hp[(size_t)s3 * HD + off];
        a0 += unpackf(u0.x) + unpackf(u1.x) + unpackf(u2.x) + unpackf(u3.x);
        a1 += unpackf(u0.y) + unpackf(u1.y) + unpackf(u2.y) + unpackf(u3.y);
    }
    for (; j + 2 <= end; j += 2) {
        int s0 = esrc[j], s1 = esrc[j + 1];
        uint2 u0 = *(const uint2*)&hp[(size_t)s0 * HD + off];
        uint2 u1 = *(const uint2*)&hp[(size_t)s1 * HD + off];
        a0 += unpackf(u0.x) + unpackf(u1.x);
        a1 += unpackf(u0.y) + unpackf(u1.y);
    }
    if (j < end) {
        uint2 u0 = *(const uint2*)&hp[(size_t)esrc[j] * HD + off];
        a0 += unpackf(u0.x);
        a1 += unpackf(u0.y);
    }
    *(uint2*)&aggp[(size_t)v * HD + off] = make_uint2(packf(a0), packf(a1));
}

// ---------------- fused GRU via MFMA, 2-phase double-buffered LDS staging ----------------
// gates[N,384] = [agg | h] @ [Wmi ; Whh], split-bf16 3-term MFMA, in-register epilogue.
// block: 512 thr = 8 waves (wr in 0..3 row-groups of 32, wc in {0,1} col-half), tile 128 rows.
// 16 phases: (src 0..1) x (sl 0..3) x (half hi/lo); 24KB half-slice per phase, 2x24KB ping-pong.
__global__ __launch_bounds__(512, 4) void k_gru_mfma(const uint_t* __restrict__ aggp,
                                                     uint_t* __restrict__ hp,
                                                     const ushort_t* __restrict__ BmHi,
                                                     const ushort_t* __restrict__ BmLo,
                                                     const ushort_t* __restrict__ BhHi,
                                                     const ushort_t* __restrict__ BhLo,
                                                     const float* __restrict__ bih,
                                                     const float* __restrict__ bhh) {
    __shared__ __align__(16) ushort_t bsm[2][12288];  // 2 x 24KB half-slice buffers
    int t = threadIdx.x;          // 0..511
    int lane = t & 63;
    int wid = t >> 6;             // 0..7
    int wr = wid >> 1, wc = wid & 1;
    int row_base = blockIdx.x * GRU_ROWS + wr * 32;
    int ar0 = min(row_base + (lane & 15), N_NODES - 1);
    int ar1 = min(row_base + 16 + (lane & 15), N_NODES - 1);
    int kcol = (lane >> 4) * 8;

    f32x4 accR[2][4], accZ[2][4], accXN[2][4], accHN[2][4];
#pragma unroll
    for (int rf = 0; rf < 2; ++rf)
#pragma unroll
        for (int q = 0; q < 4; ++q) {
            accR[rf][q] = (f32x4)0.f; accZ[rf][q] = (f32x4)0.f;
            accXN[rf][q] = (f32x4)0.f; accHN[rf][q] = (f32x4)0.f;
        }

    // prologue: A fragments for group 0 (src=0/agg, sl=0) + stage phase 0 (Bm hi, sl 0)
    uint8v u0c = *(const uint8v*)&aggp[(size_t)ar0 * HD + kcol];
    uint8v u1c = *(const uint8v*)&aggp[(size_t)ar1 * HD + kcol];
    {
        const uint4* g = (const uint4*)BmHi;  // sl=0 slice
        uint4 s0 = g[t], s1 = g[t + 512], s2 = g[t + 1024];
        uint4* d = (uint4*)bsm[0];
        d[t] = s0; d[t + 512] = s1; d[t + 1024] = s2;
    }
    __syncthreads();

    uint8v u0n = u0c, u1n = u1c;
#pragma unroll
    for (int p = 0; p < 16; ++p) {
        const int k = p >> 1;
        const int src = k >> 2;       // 0: agg/Wmi, 1: h/Whh
        const int half = p & 1;       // 0: Bhi (2 terms), 1: Blo (1 term)
        // --- issue next-phase staging loads (global -> regs) ---
        uint4 s0, s1, s2;
        if (p < 15) {
            const int k2 = (p + 1) >> 1, src2 = k2 >> 2, sl2 = k2 & 3, half2 = (p + 1) & 1;
            const ushort_t* base = src2 ? (half2 ? BhLo : BhHi) : (half2 ? BmLo : BmHi);
            const uint4* g = (const uint4*)(base + (size_t)sl2 * 12288);
            s0 = g[t]; s1 = g[t + 512]; s2 = g[t + 1024];
        }
        // --- issue next-group A loads during the lo phase ---
        if (half == 1 && k < 7) {
            const int k2 = k + 1, src2 = k2 >> 2, sl2 = k2 & 3;
            const uint_t* Ap2 = src2 ? hp : aggp;
            const int kb2 = sl2 * 32 + kcol;
            u0n = *(const uint8v*)&Ap2[(size_t)ar0 * HD + kb2];
            u1n = *(const uint8v*)&Ap2[(size_t)ar1 * HD + kb2];
        }
        // --- compute from bsm[p&1] ---
        short8v a0h, a0l, a1h, a1l;
#pragma unroll
        for (int j = 0; j < 8; ++j) {
            a0h[j] = (short)(u0c[j] >> 16); a0l[j] = (short)(u0c[j] & 0xffffu);
            a1h[j] = (short)(u1c[j] >> 16); a1l[j] = (short)(u1c[j] & 0xffffu);
        }
        const ushort_t* bb = bsm[p & 1];
#pragma unroll
        for (int grp = 0; grp < 3; ++grp) {
            auto& gate = (grp == 0) ? accR : (grp == 1) ? accZ : (src == 0) ? accXN : accHN;
#pragma unroll
            for (int q = 0; q < 4; ++q) {
                int tt = grp * 8 + wc * 4 + q;
                short8v b = *(const short8v*)&bb[(tt * 64 + lane) * 8];
                if (half == 0) {
                    gate[0][q] = mfma16(a0h, b, gate[0][q]);
                    gate[0][q] = mfma16(a0l, b, gate[0][q]);
                    gate[1][q] = mfma16(a1h, b, gate[1][q]);
                    gate[1][q] = mfma16(a1l, b, gate[1][q]);
                } else {
                    gate[0][q] = mfma16(a0h, b, gate[0][q]);
                    gate[1][q] = mfma16(a1h, b, gate[1][q]);
                }
            }
        }
        // --- write staged data into the other buffer ---
        if (p < 15) {
            uint4* d = (uint4*)bsm[(p + 1) & 1];
            d[t] = s0; d[t + 512] = s1; d[t + 1024] = s2;
        }
        __syncthreads();
        if (half == 1) { u0c = u0n; u1c = u1n; }
    }

#pragma unroll
    for (int rf = 0; rf < 2; ++rf) {
#pragma unroll
        for (int q = 0; q < 4; ++q) {
            int c = wc * 64 + q * 16 + (lane & 15);
            float bir = bih[c],       bhr = bhh[c];
            float biz = bih[c + 128], bhz = bhh[c + 128];
            float bin_ = bih[c + 256], bhn = bhh[c + 256];
#pragma unroll
            for (int j = 0; j < 4; ++j) {
                int row = row_base + rf * 16 + ((lane >> 4) << 2) + j;
                if (row < N_NODES) {
                    float rr = sigmoid_(accR[rf][q][j] + bir + bhr);
                    float zz = sigmoid_(accZ[rf][q][j] + biz + bhz);
                    float nn = tanhf(accXN[rf][q][j] + bin_ + rr * (accHN[rf][q][j] + bhn));
                    size_t idx = (size_t)row * HD + c;
                    float hold = unpackf(hp[idx]);
                    hp[idx] = packf((1.f - zz) * nn + zz * hold);
                }
            }
        }
    }
}

// ---------------- pooling ----------------
#define POOL_CHUNK 256
__global__ __launch_bounds__(128) void k_pool(const uint_t* __restrict__ hp,
                                              const int* __restrict__ batch,
                                              float* __restrict__ pooled) {
    int t = threadIdx.x;  // 128 cols
    int n0 = blockIdx.x * POOL_CHUNK;
    int nend = n0 + POOL_CHUNK;
    if (nend > N_NODES) nend = N_NODES;
    float acc = 0.f;
    int cur = batch[n0];
    for (int n = n0; n < nend; ++n) {
        int g = batch[n];
        if (g != cur) {
            atomicAdd(&pooled[(size_t)cur * HD + t], acc);
            acc = 0.f;
            cur = g;
        }
        acc += fmaxf(unpackf(hp[(size_t)n * HD + t]), 0.f);  // fused final relu
    }
    atomicAdd(&pooled[(size_t)cur * HD + t], acc);
}

// ---------------- output MLP (counts via binary search on sorted batch) ----------------
__global__ __launch_bounds__(128) void k_out(const float* __restrict__ pooled,
                                             const int* __restrict__ batch,
                                             const float* __restrict__ W1,
                                             const float* __restrict__ b1,
                                             const float* __restrict__ W2,
                                             const float* __restrict__ b2,
                                             float* __restrict__ out) {
    __shared__ float row[128];
    __shared__ float red[128];
    int t = threadIdx.x;
    int g = blockIdx.x;
    int lo0 = 0, hi0 = N_NODES;
    while (lo0 < hi0) { int mid = (lo0 + hi0) >> 1; if (batch[mid] < g) lo0 = mid + 1; else hi0 = mid; }
    int lo1 = lo0, hi1 = N_NODES;
    while (lo1 < hi1) { int mid = (lo1 + hi1) >> 1; if (batch[mid] < g + 1) lo1 = mid + 1; else hi1 = mid; }
    float cnt = (float)(lo1 - lo0);
    if (cnt < 1.f) cnt = 1.f;
    row[t] = pooled[(size_t)g * HD + t] / cnt;
    __syncthreads();
    float acc = b1[t];
#pragma unroll 4
    for (int k = 0; k < HD; ++k) acc += row[k] * W1[k * HD + t];
    float hv = fmaxf(acc, 0.f);
    red[t] = hv * W2[t];
    __syncthreads();
    for (int off = 64; off > 0; off >>= 1) {
        if (t < off) red[t] += red[t + off];
        __syncthreads();
    }
    if (t == 0) {
        float xv = red[0] + b2[0];
        out[g] = fmaxf(xv, 0.f) + log1pf(expf(-fabsf(xv)));
    }
}

extern "C" void kernel_launch(void* const* d_in, const int* in_sizes, int n_in,
                              void* d_out, int out_size, void* d_ws, size_t ws_size,
                              hipStream_t stream) {
    (void)in_sizes; (void)n_in; (void)out_size; (void)ws_size;
    const float* x    = (const float*)d_in[0];
    const int*   ei   = (const int*)d_in[1];
    const int*   batch= (const int*)d_in[2];
    const float* Wemb = (const float*)d_in[3];
    const float* Wmsg = (const float*)d_in[4];
    const float* Wih  = (const float*)d_in[5];
    const float* Whh  = (const float*)d_in[6];
    const float* bih  = (const float*)d_in[7];
    const float* bhh  = (const float*)d_in[8];
    const float* W1   = (const float*)d_in[9];
    const float* b1   = (const float*)d_in[10];
    const float* W2   = (const float*)d_in[11];
    const float* b2   = (const float*)d_in[12];
    float* out = (float*)d_out;

    const int* e_src = ei;
    const int* e_dst = ei + N_EDGES;

    char* ws = (char*)d_ws;
    size_t off = 0;
    auto alloc = [&](size_t bytes) -> void* {
        void* p = ws + off;
        off = (off + bytes + 255) & ~(size_t)255;
        return p;
    };
    uint_t* hp       = (uint_t*)alloc((size_t)N_NODES * HD * 4);
    uint_t* aggp     = (uint_t*)alloc((size_t)N_NODES * HD * 4);
    float* Wmi       = (float*)alloc((size_t)STEPS * 128 * 384 * 4);
    ushort_t* BmHi   = (ushort_t*)alloc((size_t)STEPS * 128 * 384 * 2);
    ushort_t* BmLo   = (ushort_t*)alloc((size_t)STEPS * 128 * 384 * 2);
    ushort_t* BhHi   = (ushort_t*)alloc((size_t)128 * 384 * 2);
    ushort_t* BhLo   = (ushort_t*)alloc((size_t)128 * 384 * 2);
    float* pooled    = (float*)alloc((size_t)N_GRAPHS * HD * 4);
    int* deg         = (int*)alloc((size_t)N_NODES * 4);
    int* row_start   = (int*)alloc((size_t)(N_NODES + 1) * 4);
    int* cursor      = (int*)alloc((size_t)N_NODES * 4);
    int* esrc        = (int*)alloc((size_t)N_EDGES * 4);
    int* bsum        = (int*)alloc((size_t)SCAN_BLOCKS * 4);
    int* bpre        = (int*)alloc((size_t)SCAN_BLOCKS * 4);

    hipMemsetAsync(deg, 0, (size_t)N_NODES * 4, stream);
    hipMemsetAsync(pooled, 0, (size_t)N_GRAPHS * HD * 4, stream);

    k_count<<<(N_EDGES + 255) / 256, 256, 0, stream>>>(e_dst, deg);
    k_bsum<<<SCAN_BLOCKS, 256, 0, stream>>>(deg, bsum);
    k_bscan<<<1, 256, 0, stream>>>(bsum, bpre);
    k_wscan<<<SCAN_BLOCKS, 256, 0, stream>>>(deg, bpre, row_start, cursor);
    k_fill<<<(N_EDGES + 255) / 256, 256, 0, stream>>>(e_src, e_dst, cursor, esrc);

    k_wmi<<<STEPS * 128 * 3, 128, 0, stream>>>(Wmsg, Wih, Wmi);
    k_packB<<<dim3(24, 5), 256, 0, stream>>>(Wmi, Whh, BmHi, BmLo, BhHi, BhLo);

    k_embed<<<(N_NODES + 31) / 32, 256, 0, stream>>>(x, Wemb, hp);

    for (int i = 0; i < STEPS; ++i) {
        k_gather<<<N_NODES / 4, 256, 0, stream>>>(hp, row_start, esrc, aggp);
        k_gru_mfma<<<(N_NODES + GRU_ROWS - 1) / GRU_ROWS, 512, 0, stream>>>(
            aggp, hp,
            BmHi + (size_t)i * 49152, BmLo + (size_t)i * 49152,
            BhHi, BhLo, bih, bhh);
    }

    k_pool<<<(N_NODES + POOL_CHUNK - 1) / POOL_CHUNK, 128, 0, stream>>>(hp, batch, pooled);
    k_out<<<N_GRAPHS, 128, 0, stream>>>(pooled, batch, W1, b1, W2, b2, out);
}